// Round 2
// baseline (1523.738 us; speedup 1.0000x reference)
//
#include <hip/hip_runtime.h>

// ---------------------------------------------------------------------------
// GIN (5 layers) + BN + graph pooling + MLP head, fp32.
// R2: matvec LDS-pipe bottleneck removed. Per layer, one block = 64-node tile:
//   phase A (lane=channel): CSR gather s = v_i + sum_j v_j, h2 = a*s+b*(1+deg),
//           write into 16KB LDS tile (XOR-quad swizzled, pitch 64).
//   phase B (lane=node): each lane holds its node's h[64] in VGPRs; weights
//           read as wave-uniform scalar loads (s_load through K$); the 4 waves
//           split the 64 output channels (16 each). Pure-VALU matvecs.
//   phase C (lane=channel): dwordx4 store + BN stats (32-bucket atomics) +
//           per-graph pooling with boundary flush.
// ---------------------------------------------------------------------------

#define SCAN_ELEMS 1024

__global__ __launch_bounds__(256) void k_hist(const int* __restrict__ dst, int E,
        int* __restrict__ cnt_node, const int* __restrict__ batch, int N,
        int* __restrict__ cnt_graph) {
    int i = blockIdx.x * blockDim.x + threadIdx.x;
    if (i < E) atomicAdd(&cnt_node[dst[i]], 1);
    if (i < N) atomicAdd(&cnt_graph[batch[i]], 1);
}

__global__ __launch_bounds__(256) void k_scan1(const int* __restrict__ cnt, int n,
        int* __restrict__ rp, int* __restrict__ bsum) {
    __shared__ int sdata[256];
    int t = threadIdx.x;
    int base = blockIdx.x * SCAN_ELEMS + t * 4;
    int v0 = (base + 0 < n) ? cnt[base + 0] : 0;
    int v1 = (base + 1 < n) ? cnt[base + 1] : 0;
    int v2 = (base + 2 < n) ? cnt[base + 2] : 0;
    int v3 = (base + 3 < n) ? cnt[base + 3] : 0;
    int tsum = v0 + v1 + v2 + v3;
    sdata[t] = tsum;
    __syncthreads();
    for (int off = 1; off < 256; off <<= 1) {
        int val = (t >= off) ? sdata[t - off] : 0;
        __syncthreads();
        sdata[t] += val;
        __syncthreads();
    }
    int excl = sdata[t] - tsum;
    if (t == 255) bsum[blockIdx.x] = sdata[255];
    if (base + 0 < n) rp[base + 0] = excl;
    if (base + 1 < n) rp[base + 1] = excl + v0;
    if (base + 2 < n) rp[base + 2] = excl + v0 + v1;
    if (base + 3 < n) rp[base + 3] = excl + v0 + v1 + v2;
}

__global__ __launch_bounds__(128) void k_scan2(const int* __restrict__ bsum, int nb,
        int* __restrict__ boffs) {
    __shared__ int sd[128];
    int t = threadIdx.x;
    int v = (t < nb) ? bsum[t] : 0;
    sd[t] = v;
    __syncthreads();
    for (int off = 1; off < 128; off <<= 1) {
        int val = (t >= off) ? sd[t - off] : 0;
        __syncthreads();
        sd[t] += val;
        __syncthreads();
    }
    if (t < nb) boffs[t] = sd[t] - v;
}

__global__ __launch_bounds__(256) void k_scan3(int* __restrict__ rp, int n,
        const int* __restrict__ boffs, int E) {
    int i = blockIdx.x * blockDim.x + threadIdx.x;
    if (i < n) rp[i] += boffs[i / SCAN_ELEMS];
    if (i == 0) rp[n] = E;
}

__global__ __launch_bounds__(256) void k_fill(const int* __restrict__ src,
        const int* __restrict__ dst, int E, const int* __restrict__ rp,
        int* __restrict__ cursor, int* __restrict__ col) {
    int e = blockIdx.x * blockDim.x + threadIdx.x;
    if (e < E) {
        int d = dst[e];
        int pos = rp[d] + atomicAdd(&cursor[d], 1);
        col[pos] = src[e];
    }
}

// y = x @ W1a  (x: [N,11], W1a: [11,64]); weights in VGPRs, x via scalar loads
__global__ __launch_bounds__(256) void k_premm(const float* __restrict__ x,
        const float* __restrict__ W1a, float* __restrict__ y, int N) {
    int lane = threadIdx.x & 63, wv = threadIdx.x >> 6;
    float w[11];
#pragma unroll
    for (int k = 0; k < 11; ++k) w[k] = W1a[k * 64 + lane];
    int wg = blockIdx.x * 4 + wv, ws = gridDim.x * 4;
    for (int i = wg; i < N; i += ws) {
        float acc = 0.f;
#pragma unroll
        for (int k = 0; k < 11; ++k) acc = fmaf(x[i * 11 + k], w[k], acc);
        y[i * 64 + lane] = acc;
    }
}

// One GIN layer, one block = one 64-node tile.
template <bool FIRST>
__global__ __launch_bounds__(256, 4) void k_layer(
        const float* __restrict__ vin, float* __restrict__ vout,
        const int* __restrict__ rp, const int* __restrict__ col,
        const int* __restrict__ batch,
        const float* __restrict__ ab_prev,
        const float* __restrict__ Wa, const float* __restrict__ ba,
        const float* __restrict__ Wb, const float* __restrict__ bb,
        float* __restrict__ Sg, float* __restrict__ bnpart,
        int N) {
    __shared__ float hb[64 * 64];
    float4* hb4 = (float4*)hb;
    const int tid = threadIdx.x;
    const int lane = tid & 63;
    const int wv = tid >> 6;
    const int n0 = blockIdx.x * 64;

    // ---- phase A: gather (lane = channel), wave wv does tile nodes wv*16.. ----
    {
        float a = 1.f, b = 0.f;
        if (!FIRST) { a = ab_prev[lane]; b = ab_prev[64 + lane]; }
        for (int t = 0; t < 16; ++t) {
            int nt = wv * 16 + t;
            int n = n0 + nt;
            if (n < N) {
                int start = rp[n], end = rp[n + 1];
                float s0 = vin[n * 64 + lane];
                float s1 = 0.f, s2 = 0.f, s3 = 0.f;
                int e = start;
                for (; e + 4 <= end; e += 4) {
                    int j0 = col[e], j1 = col[e + 1], j2 = col[e + 2], j3 = col[e + 3];
                    s0 += vin[j0 * 64 + lane];
                    s1 += vin[j1 * 64 + lane];
                    s2 += vin[j2 * 64 + lane];
                    s3 += vin[j3 * 64 + lane];
                }
                for (; e < end; ++e) s0 += vin[col[e] * 64 + lane];
                float s = (s0 + s1) + (s2 + s3);
                float h2 = FIRST ? s : fmaf(a, s, b * (float)(1 + end - start));
                int pq = (lane >> 2) ^ (nt & 15);
                hb[nt * 64 + pq * 4 + (lane & 3)] = h2;
            }
        }
    }
    __syncthreads();

    // ---- phase B: matvecs (lane = node-in-tile) ----
    float h[64];
    {
        int l15 = lane & 15;
#pragma unroll
        for (int q = 0; q < 16; ++q) {
            float4 hv = hb4[lane * 16 + (q ^ l15)];
            h[q * 4 + 0] = hv.x; h[q * 4 + 1] = hv.y;
            h[q * 4 + 2] = hv.z; h[q * 4 + 3] = hv.w;
        }
    }
    __syncthreads();   // all waves done reading hb; safe to overwrite

    const int c0 = wv * 16;
    float acc[16];
    if (FIRST) {
        // matvec1 (W1a) was folded into k_premm: t = relu(h + ba), full per lane
#pragma unroll
        for (int k = 0; k < 64; ++k) h[k] = fmaxf(h[k] + ba[k], 0.f);
    } else {
        // matvec1: t[c0+j] = relu(sum_k h[k]*Wa[k][c0+j] + ba[c0+j])
#pragma unroll
        for (int j = 0; j < 16; ++j) acc[j] = ba[c0 + j];
        for (int k = 0; k < 64; ++k) {
            float hk = h[k];
            const float* wr = Wa + k * 64 + c0;   // wave-uniform -> s_load
#pragma unroll
            for (int j = 0; j < 16; ++j) acc[j] = fmaf(hk, wr[j], acc[j]);
        }
        int l15 = lane & 15;
#pragma unroll
        for (int j4 = 0; j4 < 4; ++j4) {
            int q = wv * 4 + j4;
            hb4[lane * 16 + (q ^ l15)] = make_float4(
                fmaxf(acc[j4 * 4 + 0], 0.f), fmaxf(acc[j4 * 4 + 1], 0.f),
                fmaxf(acc[j4 * 4 + 2], 0.f), fmaxf(acc[j4 * 4 + 3], 0.f));
        }
        __syncthreads();
#pragma unroll
        for (int q = 0; q < 16; ++q) {
            float4 hv = hb4[lane * 16 + (q ^ l15)];
            h[q * 4 + 0] = hv.x; h[q * 4 + 1] = hv.y;
            h[q * 4 + 2] = hv.z; h[q * 4 + 3] = hv.w;
        }
        __syncthreads();
    }

    // matvec2: v[c0+j] = relu(sum_k t[k]*Wb[k][c0+j] + bb[c0+j])
#pragma unroll
    for (int j = 0; j < 16; ++j) acc[j] = bb[c0 + j];
    for (int k = 0; k < 64; ++k) {
        float tk = h[k];
        const float* wr = Wb + k * 64 + c0;       // wave-uniform -> s_load
#pragma unroll
        for (int j = 0; j < 16; ++j) acc[j] = fmaf(tk, wr[j], acc[j]);
    }
    {
        int l15 = lane & 15;
#pragma unroll
        for (int j4 = 0; j4 < 4; ++j4) {
            int q = wv * 4 + j4;
            hb4[lane * 16 + (q ^ l15)] = make_float4(
                fmaxf(acc[j4 * 4 + 0], 0.f), fmaxf(acc[j4 * 4 + 1], 0.f),
                fmaxf(acc[j4 * 4 + 2], 0.f), fmaxf(acc[j4 * 4 + 3], 0.f));
        }
    }
    __syncthreads();

    // ---- phase C: store + BN stats + graph pooling (lane -> 4-node groups) ----
    {
        int q = lane & 15;          // channel quad
        int ng = lane >> 4;         // node subgroup
        float4 bs = make_float4(0, 0, 0, 0), bq = make_float4(0, 0, 0, 0);
        float4 pacc = make_float4(0, 0, 0, 0);
        int curg = -1;
#pragma unroll
        for (int s2 = 0; s2 < 4; ++s2) {
            int nt = wv * 16 + s2 * 4 + ng;
            int n = n0 + nt;
            if (n < N) {
                float4 v = hb4[nt * 16 + (q ^ (nt & 15))];
                *(float4*)(vout + n * 64 + q * 4) = v;
                bs.x += v.x; bs.y += v.y; bs.z += v.z; bs.w += v.w;
                bq.x += v.x * v.x; bq.y += v.y * v.y;
                bq.z += v.z * v.z; bq.w += v.w * v.w;
                int g = batch[n];
                if (g != curg) {
                    if (curg >= 0) {
                        atomicAdd(&Sg[curg * 64 + q * 4 + 0], pacc.x);
                        atomicAdd(&Sg[curg * 64 + q * 4 + 1], pacc.y);
                        atomicAdd(&Sg[curg * 64 + q * 4 + 2], pacc.z);
                        atomicAdd(&Sg[curg * 64 + q * 4 + 3], pacc.w);
                    }
                    curg = g;
                    pacc = make_float4(0, 0, 0, 0);
                }
                pacc.x += v.x; pacc.y += v.y; pacc.z += v.z; pacc.w += v.w;
            }
        }
        if (curg >= 0) {
            atomicAdd(&Sg[curg * 64 + q * 4 + 0], pacc.x);
            atomicAdd(&Sg[curg * 64 + q * 4 + 1], pacc.y);
            atomicAdd(&Sg[curg * 64 + q * 4 + 2], pacc.z);
            atomicAdd(&Sg[curg * 64 + q * 4 + 3], pacc.w);
        }
        // reduce stats across the 4 node subgroups (lanes with same q)
#pragma unroll
        for (int off = 16; off < 64; off <<= 1) {
            bs.x += __shfl_xor(bs.x, off); bs.y += __shfl_xor(bs.y, off);
            bs.z += __shfl_xor(bs.z, off); bs.w += __shfl_xor(bs.w, off);
            bq.x += __shfl_xor(bq.x, off); bq.y += __shfl_xor(bq.y, off);
            bq.z += __shfl_xor(bq.z, off); bq.w += __shfl_xor(bq.w, off);
        }
        if (ng == 0) {
            float* bkt = bnpart + (blockIdx.x & 31) * 128;
            atomicAdd(&bkt[q * 4 + 0], bs.x);
            atomicAdd(&bkt[q * 4 + 1], bs.y);
            atomicAdd(&bkt[q * 4 + 2], bs.z);
            atomicAdd(&bkt[q * 4 + 3], bs.w);
            atomicAdd(&bkt[64 + q * 4 + 0], bq.x);
            atomicAdd(&bkt[64 + q * 4 + 1], bq.y);
            atomicAdd(&bkt[64 + q * 4 + 2], bq.z);
            atomicAdd(&bkt[64 + q * 4 + 3], bq.w);
        }
    }
}

__global__ void k_bnstat(const float* __restrict__ bnpart,
        const float* __restrict__ gamma, const float* __restrict__ beta,
        float* __restrict__ a, float* __restrict__ b, int N) {
    int c = threadIdx.x;  // 64 threads
    float s = 0.f, q = 0.f;
    for (int i = 0; i < 32; ++i) { s += bnpart[i * 128 + c]; q += bnpart[i * 128 + 64 + c]; }
    float invN = 1.0f / (float)N;
    float mu = s * invN;
    float var = q * invN - mu * mu;
    float ac = gamma[c] * rsqrtf(var + 1e-5f);
    a[c] = ac;
    b[c] = beta[c] - mu * ac;
}

// Head: z[g,320] = concat_l (a_l*S_l[g] + b_l*cnt[g]); out = relu(z@fc1+b)@fc2+b
__global__ __launch_bounds__(256) void k_final(
        const float* __restrict__ S, const float* __restrict__ ab,
        const int* __restrict__ cntg,
        const float* __restrict__ fc1W, const float* __restrict__ fc1b,
        const float* __restrict__ fc2W, const float* __restrict__ fc2b,
        float* __restrict__ out, int G) {
    __shared__ float zbuf[4][320];
    int tid = threadIdx.x;
    int lane = tid & 63, wv = tid >> 6;
    int g = blockIdx.x * 4 + wv;
    if (g >= G) return;
    float cf = (float)cntg[g];
#pragma unroll
    for (int l = 0; l < 5; ++l) {
        float a = ab[l * 128 + lane];
        float b = ab[l * 128 + 64 + lane];
        zbuf[wv][l * 64 + lane] = a * S[((size_t)l * G + g) * 64 + lane] + b * cf;
    }
    float acc = fc1b[lane];
    for (int k = 0; k < 320; ++k) acc += zbuf[wv][k] * fc1W[k * 64 + lane];
    float t = fmaxf(acc, 0.f);
    float r = t * fc2W[lane];
#pragma unroll
    for (int off = 32; off >= 1; off >>= 1) r += __shfl_xor(r, off);
    if (lane == 0) out[g] = r + fc2b[0];
}

extern "C" void kernel_launch(void* const* d_in, const int* in_sizes, int n_in,
                              void* d_out, int out_size, void* d_ws, size_t ws_size,
                              hipStream_t stream) {
    const float* x    = (const float*)d_in[0];
    const int*   ei   = (const int*)d_in[1];
    const int*   batch= (const int*)d_in[2];
    const float* W1a  = (const float*)d_in[3];
    const float* b1a  = (const float*)d_in[4];
    const float* W1b  = (const float*)d_in[5];
    const float* b1b  = (const float*)d_in[6];
    const float* Wa   = (const float*)d_in[7];
    const float* ba   = (const float*)d_in[8];
    const float* Wb   = (const float*)d_in[9];
    const float* bb   = (const float*)d_in[10];
    const float* gamma= (const float*)d_in[11];
    const float* beta = (const float*)d_in[12];
    const float* fc1W = (const float*)d_in[13];
    const float* fc1b = (const float*)d_in[14];
    const float* fc2W = (const float*)d_in[15];
    const float* fc2b = (const float*)d_in[16];

    const int N = in_sizes[2];
    const int E = in_sizes[1] / 2;
    const int G = out_size;
    const int* srcp = ei;
    const int* dstp = ei + E;

    char* p = (char*)d_ws;
    auto alloc = [&](size_t bytes) {
        char* r = p;
        p += (bytes + 255) & ~size_t(255);
        return r;
    };
    float* B0     = (float*)alloc((size_t)N * 64 * 4);
    float* B1     = (float*)alloc((size_t)N * 64 * 4);
    int*   col    = (int*)  alloc((size_t)E * 4);
    int*   rp     = (int*)  alloc((size_t)(N + 1) * 4);
    int*   cntn   = (int*)  alloc((size_t)N * 4);
    int*   cursor = (int*)  alloc((size_t)N * 4);
    int*   bsum   = (int*)  alloc(512);
    int*   boffs  = (int*)  alloc(512);
    int*   cntg   = (int*)  alloc((size_t)G * 4);
    float* S      = (float*)alloc((size_t)5 * G * 64 * 4);
    float* bnpart = (float*)alloc((size_t)5 * 32 * 128 * 4);
    float* ab     = (float*)alloc(5 * 128 * 4);

    hipMemsetAsync(cntn,   0, (size_t)N * 4, stream);
    hipMemsetAsync(cursor, 0, (size_t)N * 4, stream);
    hipMemsetAsync(cntg,   0, (size_t)G * 4, stream);
    hipMemsetAsync(S,      0, (size_t)5 * G * 64 * 4, stream);
    hipMemsetAsync(bnpart, 0, (size_t)5 * 32 * 128 * 4, stream);

    int nb_e = (E + 255) / 256;
    int nb_scan = (N + SCAN_ELEMS - 1) / SCAN_ELEMS;
    k_hist<<<nb_e, 256, 0, stream>>>(dstp, E, cntn, batch, N, cntg);
    k_scan1<<<nb_scan, 256, 0, stream>>>(cntn, N, rp, bsum);
    k_scan2<<<1, 128, 0, stream>>>(bsum, nb_scan, boffs);
    k_scan3<<<(N + 255) / 256, 256, 0, stream>>>(rp, N, boffs, E);
    k_fill<<<nb_e, 256, 0, stream>>>(srcp, dstp, E, rp, cursor, col);

    k_premm<<<512, 256, 0, stream>>>(x, W1a, B0, N);

    int nb_tile = (N + 63) / 64;
    // Layer 1 (W1a folded into k_premm)
    k_layer<true><<<nb_tile, 256, 0, stream>>>(B0, B1, rp, col, batch,
        nullptr, nullptr, b1a, W1b, b1b,
        S, bnpart, N);
    k_bnstat<<<1, 64, 0, stream>>>(bnpart, gamma, beta, ab, ab + 64, N);

    const float* vin = B1;
    float* vout = B0;
    for (int l = 0; l < 4; ++l) {
        k_layer<false><<<nb_tile, 256, 0, stream>>>(vin, vout, rp, col, batch,
            ab + l * 128,
            Wa + l * 4096, ba + l * 64, Wb + l * 4096, bb + l * 64,
            S + (size_t)(l + 1) * G * 64,
            bnpart + (size_t)(l + 1) * 32 * 128, N);
        k_bnstat<<<1, 64, 0, stream>>>(
            bnpart + (size_t)(l + 1) * 32 * 128,
            gamma + (l + 1) * 64, beta + (l + 1) * 64,
            ab + (l + 1) * 128, ab + (l + 1) * 128 + 64, N);
        float* t = vout; vout = (float*)vin; vin = t;
    }

    k_final<<<(G + 3) / 4, 256, 0, stream>>>(S, ab, cntg, fc1W, fc1b, fc2W, fc2b,
                                             (float*)d_out, G);
}

// Round 3
// 1394.661 us; speedup vs baseline: 1.0926x; 1.0926x over previous
//
#include <hip/hip_runtime.h>

// ---------------------------------------------------------------------------
// GIN (5 layers) + BN + graph pooling + MLP head, fp32.
// R3: layer split into (a) latency-optimized gather kernel (1 wave = 1 node,
//     8-deep load ILP, ~32 waves/CU) and (b) streaming MLP kernel (tile=64
//     nodes, LDS transpose, s_load weights, BN stats + pooling).
//     BN affine of the previous layer is folded into the gather.
// ---------------------------------------------------------------------------

#define SCAN_ELEMS 1024

__global__ __launch_bounds__(256) void k_hist(const int* __restrict__ dst, int E,
        int* __restrict__ cnt_node, const int* __restrict__ batch, int N,
        int* __restrict__ cnt_graph) {
    int i = blockIdx.x * blockDim.x + threadIdx.x;
    if (i < E) atomicAdd(&cnt_node[dst[i]], 1);
    if (i < N) atomicAdd(&cnt_graph[batch[i]], 1);
}

__global__ __launch_bounds__(256) void k_scan1(const int* __restrict__ cnt, int n,
        int* __restrict__ rp, int* __restrict__ bsum) {
    __shared__ int sdata[256];
    int t = threadIdx.x;
    int base = blockIdx.x * SCAN_ELEMS + t * 4;
    int v0 = (base + 0 < n) ? cnt[base + 0] : 0;
    int v1 = (base + 1 < n) ? cnt[base + 1] : 0;
    int v2 = (base + 2 < n) ? cnt[base + 2] : 0;
    int v3 = (base + 3 < n) ? cnt[base + 3] : 0;
    int tsum = v0 + v1 + v2 + v3;
    sdata[t] = tsum;
    __syncthreads();
    for (int off = 1; off < 256; off <<= 1) {
        int val = (t >= off) ? sdata[t - off] : 0;
        __syncthreads();
        sdata[t] += val;
        __syncthreads();
    }
    int excl = sdata[t] - tsum;
    if (t == 255) bsum[blockIdx.x] = sdata[255];
    if (base + 0 < n) rp[base + 0] = excl;
    if (base + 1 < n) rp[base + 1] = excl + v0;
    if (base + 2 < n) rp[base + 2] = excl + v0 + v1;
    if (base + 3 < n) rp[base + 3] = excl + v0 + v1 + v2;
}

__global__ __launch_bounds__(128) void k_scan2(const int* __restrict__ bsum, int nb,
        int* __restrict__ boffs) {
    __shared__ int sd[128];
    int t = threadIdx.x;
    int v = (t < nb) ? bsum[t] : 0;
    sd[t] = v;
    __syncthreads();
    for (int off = 1; off < 128; off <<= 1) {
        int val = (t >= off) ? sd[t - off] : 0;
        __syncthreads();
        sd[t] += val;
        __syncthreads();
    }
    if (t < nb) boffs[t] = sd[t] - v;
}

__global__ __launch_bounds__(256) void k_scan3(int* __restrict__ rp, int n,
        const int* __restrict__ boffs, int E) {
    int i = blockIdx.x * blockDim.x + threadIdx.x;
    if (i < n) rp[i] += boffs[i / SCAN_ELEMS];
    if (i == 0) rp[n] = E;
}

__global__ __launch_bounds__(256) void k_fill(const int* __restrict__ src,
        const int* __restrict__ dst, int E, const int* __restrict__ rp,
        int* __restrict__ cursor, int* __restrict__ col) {
    int e = blockIdx.x * blockDim.x + threadIdx.x;
    if (e < E) {
        int d = dst[e];
        int pos = rp[d] + atomicAdd(&cursor[d], 1);
        col[pos] = src[e];
    }
}

// y = x @ W1a  (x: [N,11], W1a: [11,64]); weights in VGPRs, x via scalar loads
__global__ __launch_bounds__(256) void k_premm(const float* __restrict__ x,
        const float* __restrict__ W1a, float* __restrict__ y, int N) {
    int lane = threadIdx.x & 63, wv = threadIdx.x >> 6;
    float w[11];
#pragma unroll
    for (int k = 0; k < 11; ++k) w[k] = W1a[k * 64 + lane];
    int wg = blockIdx.x * 4 + wv, ws = gridDim.x * 4;
    for (int i = wg; i < N; i += ws) {
        float acc = 0.f;
#pragma unroll
        for (int k = 0; k < 11; ++k) acc = fmaf(x[i * 11 + k], w[k], acc);
        y[i * 64 + lane] = acc;
    }
}

// Gather: one wave per node, lane = channel. s = v_n + sum_j v_j.
// Folds previous-layer BN affine: h2 = a*s + b*(1+deg). 8-deep load ILP.
template <bool FIRST>
__global__ __launch_bounds__(256, 8) void k_gather(
        const float* __restrict__ vin, float* __restrict__ agg,
        const int* __restrict__ rp, const int* __restrict__ col,
        const float* __restrict__ ab_prev, int N) {
    int lane = threadIdx.x & 63, wv = threadIdx.x >> 6;
    int n = blockIdx.x * 4 + wv;
    if (n >= N) return;
    float a = 1.f, b = 0.f;
    if (!FIRST) { a = ab_prev[lane]; b = ab_prev[64 + lane]; }
    int start = rp[n], end = rp[n + 1];
    float s0 = vin[(size_t)n * 64 + lane];
    float s1 = 0.f, s2 = 0.f, s3 = 0.f, s4 = 0.f, s5 = 0.f, s6 = 0.f, s7 = 0.f;
    int e = start;
    for (; e + 8 <= end; e += 8) {
        int j0 = col[e + 0], j1 = col[e + 1], j2 = col[e + 2], j3 = col[e + 3];
        int j4 = col[e + 4], j5 = col[e + 5], j6 = col[e + 6], j7 = col[e + 7];
        s0 += vin[(size_t)j0 * 64 + lane];
        s1 += vin[(size_t)j1 * 64 + lane];
        s2 += vin[(size_t)j2 * 64 + lane];
        s3 += vin[(size_t)j3 * 64 + lane];
        s4 += vin[(size_t)j4 * 64 + lane];
        s5 += vin[(size_t)j5 * 64 + lane];
        s6 += vin[(size_t)j6 * 64 + lane];
        s7 += vin[(size_t)j7 * 64 + lane];
    }
    for (; e < end; ++e) s0 += vin[(size_t)col[e] * 64 + lane];
    float s = ((s0 + s1) + (s2 + s3)) + ((s4 + s5) + (s6 + s7));
    float h2 = FIRST ? s : fmaf(a, s, b * (float)(1 + end - start));
    agg[(size_t)n * 64 + lane] = h2;
}

// MLP: one block = one 64-node tile. Streaming: agg -> (matvecs) -> vout,
// plus BN stats (32-bucket atomics) and per-graph pooling.
template <bool FIRST>
__global__ __launch_bounds__(256, 4) void k_mlp(
        const float* __restrict__ agg, float* __restrict__ vout,
        const int* __restrict__ batch,
        const float* __restrict__ Wa, const float* __restrict__ ba,
        const float* __restrict__ Wb, const float* __restrict__ bb,
        float* __restrict__ Sg, float* __restrict__ bnpart,
        int N) {
    __shared__ float hb[64 * 64];
    float4* hb4 = (float4*)hb;
    const int tid = threadIdx.x;
    const int lane = tid & 63;
    const int wv = tid >> 6;
    const int n0 = blockIdx.x * 64;

    // ---- phase A: coalesced tile load -> LDS (swizzled) ----
    {
        const float4* a4 = (const float4*)(agg + (size_t)n0 * 64);
#pragma unroll
        for (int r = 0; r < 4; ++r) {
            int i = tid + r * 256;          // float4 index within tile
            int nt = i >> 4, q = i & 15;
            float4 v = make_float4(0.f, 0.f, 0.f, 0.f);
            if (n0 + nt < N) v = a4[i];
            hb4[nt * 16 + (q ^ (nt & 15))] = v;
        }
    }
    __syncthreads();

    // ---- phase B: matvecs (lane = node-in-tile) ----
    float h[64];
    {
        int l15 = lane & 15;
#pragma unroll
        for (int q = 0; q < 16; ++q) {
            float4 hv = hb4[lane * 16 + (q ^ l15)];
            h[q * 4 + 0] = hv.x; h[q * 4 + 1] = hv.y;
            h[q * 4 + 2] = hv.z; h[q * 4 + 3] = hv.w;
        }
    }
    __syncthreads();   // all waves done reading hb; safe to overwrite

    const int c0 = wv * 16;
    float acc[16];
    if (FIRST) {
        // matvec1 (W1a) folded into k_premm: t = relu(h + ba)
#pragma unroll
        for (int k = 0; k < 64; ++k) h[k] = fmaxf(h[k] + ba[k], 0.f);
    } else {
#pragma unroll
        for (int j = 0; j < 16; ++j) acc[j] = ba[c0 + j];
        for (int k = 0; k < 64; ++k) {
            float hk = h[k];
            const float* wr = Wa + k * 64 + c0;   // wave-uniform -> s_load
#pragma unroll
            for (int j = 0; j < 16; ++j) acc[j] = fmaf(hk, wr[j], acc[j]);
        }
        int l15 = lane & 15;
#pragma unroll
        for (int j4 = 0; j4 < 4; ++j4) {
            int q = wv * 4 + j4;
            hb4[lane * 16 + (q ^ l15)] = make_float4(
                fmaxf(acc[j4 * 4 + 0], 0.f), fmaxf(acc[j4 * 4 + 1], 0.f),
                fmaxf(acc[j4 * 4 + 2], 0.f), fmaxf(acc[j4 * 4 + 3], 0.f));
        }
        __syncthreads();
#pragma unroll
        for (int q = 0; q < 16; ++q) {
            float4 hv = hb4[lane * 16 + (q ^ l15)];
            h[q * 4 + 0] = hv.x; h[q * 4 + 1] = hv.y;
            h[q * 4 + 2] = hv.z; h[q * 4 + 3] = hv.w;
        }
        __syncthreads();
    }

    // matvec2
#pragma unroll
    for (int j = 0; j < 16; ++j) acc[j] = bb[c0 + j];
    for (int k = 0; k < 64; ++k) {
        float tk = h[k];
        const float* wr = Wb + k * 64 + c0;       // wave-uniform -> s_load
#pragma unroll
        for (int j = 0; j < 16; ++j) acc[j] = fmaf(tk, wr[j], acc[j]);
    }
    {
        int l15 = lane & 15;
#pragma unroll
        for (int j4 = 0; j4 < 4; ++j4) {
            int q = wv * 4 + j4;
            hb4[lane * 16 + (q ^ l15)] = make_float4(
                fmaxf(acc[j4 * 4 + 0], 0.f), fmaxf(acc[j4 * 4 + 1], 0.f),
                fmaxf(acc[j4 * 4 + 2], 0.f), fmaxf(acc[j4 * 4 + 3], 0.f));
        }
    }
    __syncthreads();

    // ---- phase C: store + BN stats + graph pooling ----
    {
        int q = lane & 15;          // channel quad
        int ng = lane >> 4;         // node subgroup
        float4 bs = make_float4(0, 0, 0, 0), bq = make_float4(0, 0, 0, 0);
        float4 pacc = make_float4(0, 0, 0, 0);
        int curg = -1;
#pragma unroll
        for (int s2 = 0; s2 < 4; ++s2) {
            int nt = wv * 16 + s2 * 4 + ng;
            int n = n0 + nt;
            if (n < N) {
                float4 v = hb4[nt * 16 + (q ^ (nt & 15))];
                *(float4*)(vout + (size_t)n * 64 + q * 4) = v;
                bs.x += v.x; bs.y += v.y; bs.z += v.z; bs.w += v.w;
                bq.x += v.x * v.x; bq.y += v.y * v.y;
                bq.z += v.z * v.z; bq.w += v.w * v.w;
                int g = batch[n];
                if (g != curg) {
                    if (curg >= 0) {
                        atomicAdd(&Sg[curg * 64 + q * 4 + 0], pacc.x);
                        atomicAdd(&Sg[curg * 64 + q * 4 + 1], pacc.y);
                        atomicAdd(&Sg[curg * 64 + q * 4 + 2], pacc.z);
                        atomicAdd(&Sg[curg * 64 + q * 4 + 3], pacc.w);
                    }
                    curg = g;
                    pacc = make_float4(0, 0, 0, 0);
                }
                pacc.x += v.x; pacc.y += v.y; pacc.z += v.z; pacc.w += v.w;
            }
        }
        if (curg >= 0) {
            atomicAdd(&Sg[curg * 64 + q * 4 + 0], pacc.x);
            atomicAdd(&Sg[curg * 64 + q * 4 + 1], pacc.y);
            atomicAdd(&Sg[curg * 64 + q * 4 + 2], pacc.z);
            atomicAdd(&Sg[curg * 64 + q * 4 + 3], pacc.w);
        }
#pragma unroll
        for (int off = 16; off < 64; off <<= 1) {
            bs.x += __shfl_xor(bs.x, off); bs.y += __shfl_xor(bs.y, off);
            bs.z += __shfl_xor(bs.z, off); bs.w += __shfl_xor(bs.w, off);
            bq.x += __shfl_xor(bq.x, off); bq.y += __shfl_xor(bq.y, off);
            bq.z += __shfl_xor(bq.z, off); bq.w += __shfl_xor(bq.w, off);
        }
        if (ng == 0) {
            float* bkt = bnpart + (blockIdx.x & 31) * 128;
            atomicAdd(&bkt[q * 4 + 0], bs.x);
            atomicAdd(&bkt[q * 4 + 1], bs.y);
            atomicAdd(&bkt[q * 4 + 2], bs.z);
            atomicAdd(&bkt[q * 4 + 3], bs.w);
            atomicAdd(&bkt[64 + q * 4 + 0], bq.x);
            atomicAdd(&bkt[64 + q * 4 + 1], bq.y);
            atomicAdd(&bkt[64 + q * 4 + 2], bq.z);
            atomicAdd(&bkt[64 + q * 4 + 3], bq.w);
        }
    }
}

__global__ void k_bnstat(const float* __restrict__ bnpart,
        const float* __restrict__ gamma, const float* __restrict__ beta,
        float* __restrict__ a, float* __restrict__ b, int N) {
    int c = threadIdx.x;  // 64 threads
    float s = 0.f, q = 0.f;
    for (int i = 0; i < 32; ++i) { s += bnpart[i * 128 + c]; q += bnpart[i * 128 + 64 + c]; }
    float invN = 1.0f / (float)N;
    float mu = s * invN;
    float var = q * invN - mu * mu;
    float ac = gamma[c] * rsqrtf(var + 1e-5f);
    a[c] = ac;
    b[c] = beta[c] - mu * ac;
}

// Head: z[g,320] = concat_l (a_l*S_l[g] + b_l*cnt[g]); out = relu(z@fc1+b)@fc2+b
__global__ __launch_bounds__(256) void k_final(
        const float* __restrict__ S, const float* __restrict__ ab,
        const int* __restrict__ cntg,
        const float* __restrict__ fc1W, const float* __restrict__ fc1b,
        const float* __restrict__ fc2W, const float* __restrict__ fc2b,
        float* __restrict__ out, int G) {
    __shared__ float zbuf[4][320];
    int tid = threadIdx.x;
    int lane = tid & 63, wv = tid >> 6;
    int g = blockIdx.x * 4 + wv;
    if (g >= G) return;
    float cf = (float)cntg[g];
#pragma unroll
    for (int l = 0; l < 5; ++l) {
        float a = ab[l * 128 + lane];
        float b = ab[l * 128 + 64 + lane];
        zbuf[wv][l * 64 + lane] = a * S[((size_t)l * G + g) * 64 + lane] + b * cf;
    }
    float acc = fc1b[lane];
    for (int k = 0; k < 320; ++k) acc += zbuf[wv][k] * fc1W[k * 64 + lane];
    float t = fmaxf(acc, 0.f);
    float r = t * fc2W[lane];
#pragma unroll
    for (int off = 32; off >= 1; off >>= 1) r += __shfl_xor(r, off);
    if (lane == 0) out[g] = r + fc2b[0];
}

extern "C" void kernel_launch(void* const* d_in, const int* in_sizes, int n_in,
                              void* d_out, int out_size, void* d_ws, size_t ws_size,
                              hipStream_t stream) {
    const float* x    = (const float*)d_in[0];
    const int*   ei   = (const int*)d_in[1];
    const int*   batch= (const int*)d_in[2];
    const float* W1a  = (const float*)d_in[3];
    const float* b1a  = (const float*)d_in[4];
    const float* W1b  = (const float*)d_in[5];
    const float* b1b  = (const float*)d_in[6];
    const float* Wa   = (const float*)d_in[7];
    const float* ba   = (const float*)d_in[8];
    const float* Wb   = (const float*)d_in[9];
    const float* bb   = (const float*)d_in[10];
    const float* gamma= (const float*)d_in[11];
    const float* beta = (const float*)d_in[12];
    const float* fc1W = (const float*)d_in[13];
    const float* fc1b = (const float*)d_in[14];
    const float* fc2W = (const float*)d_in[15];
    const float* fc2b = (const float*)d_in[16];

    const int N = in_sizes[2];
    const int E = in_sizes[1] / 2;
    const int G = out_size;
    const int* srcp = ei;
    const int* dstp = ei + E;

    char* p = (char*)d_ws;
    auto alloc = [&](size_t bytes) {
        char* r = p;
        p += (bytes + 255) & ~size_t(255);
        return r;
    };
    float* B0     = (float*)alloc((size_t)N * 64 * 4);
    float* B1     = (float*)alloc((size_t)N * 64 * 4);
    int*   col    = (int*)  alloc((size_t)E * 4);
    int*   rp     = (int*)  alloc((size_t)(N + 1) * 4);
    int*   cntn   = (int*)  alloc((size_t)N * 4);
    int*   cursor = (int*)  alloc((size_t)N * 4);
    int*   bsum   = (int*)  alloc(512);
    int*   boffs  = (int*)  alloc(512);
    int*   cntg   = (int*)  alloc((size_t)G * 4);
    float* S      = (float*)alloc((size_t)5 * G * 64 * 4);
    float* bnpart = (float*)alloc((size_t)5 * 32 * 128 * 4);
    float* ab     = (float*)alloc(5 * 128 * 4);

    hipMemsetAsync(cntn,   0, (size_t)N * 4, stream);
    hipMemsetAsync(cursor, 0, (size_t)N * 4, stream);
    hipMemsetAsync(cntg,   0, (size_t)G * 4, stream);
    hipMemsetAsync(S,      0, (size_t)5 * G * 64 * 4, stream);
    hipMemsetAsync(bnpart, 0, (size_t)5 * 32 * 128 * 4, stream);

    int nb_e = (E + 255) / 256;
    int nb_scan = (N + SCAN_ELEMS - 1) / SCAN_ELEMS;
    k_hist<<<nb_e, 256, 0, stream>>>(dstp, E, cntn, batch, N, cntg);
    k_scan1<<<nb_scan, 256, 0, stream>>>(cntn, N, rp, bsum);
    k_scan2<<<1, 128, 0, stream>>>(bsum, nb_scan, boffs);
    k_scan3<<<(N + 255) / 256, 256, 0, stream>>>(rp, N, boffs, E);
    k_fill<<<nb_e, 256, 0, stream>>>(srcp, dstp, E, rp, cursor, col);

    k_premm<<<512, 256, 0, stream>>>(x, W1a, B0, N);

    int nb_node = (N + 3) / 4;
    int nb_tile = (N + 63) / 64;

    // Layer 1 (W1a folded into k_premm): gather B0 -> B1, mlp B1 -> B0
    k_gather<true><<<nb_node, 256, 0, stream>>>(B0, B1, rp, col, nullptr, N);
    k_mlp<true><<<nb_tile, 256, 0, stream>>>(B1, B0, batch,
        nullptr, b1a, W1b, b1b, S, bnpart, N);
    k_bnstat<<<1, 64, 0, stream>>>(bnpart, gamma, beta, ab, ab + 64, N);

    for (int l = 0; l < 4; ++l) {
        k_gather<false><<<nb_node, 256, 0, stream>>>(B0, B1, rp, col,
            ab + l * 128, N);
        k_mlp<false><<<nb_tile, 256, 0, stream>>>(B1, B0, batch,
            Wa + l * 4096, ba + l * 64, Wb + l * 4096, bb + l * 64,
            S + (size_t)(l + 1) * G * 64,
            bnpart + (size_t)(l + 1) * 32 * 128, N);
        k_bnstat<<<1, 64, 0, stream>>>(
            bnpart + (size_t)(l + 1) * 32 * 128,
            gamma + (l + 1) * 64, beta + (l + 1) * 64,
            ab + (l + 1) * 128, ab + (l + 1) * 128 + 64, N);
    }

    k_final<<<(G + 3) / 4, 256, 0, stream>>>(S, ab, cntg, fc1W, fc1b, fc2W, fc2b,
                                             (float*)d_out, G);
}

// Round 4
// 1313.249 us; speedup vs baseline: 1.1603x; 1.0620x over previous
//
#include <hip/hip_runtime.h>

// ---------------------------------------------------------------------------
// GIN (5 layers) + BN + graph pooling + MLP head, fp32.
// R4: k_mlp matvecs k-chunked (16 h-values at a time, fully unrolled inner
//     loops, constant LDS offsets) -> no dynamic local-array indexing, no
//     scratch spill (R3's killer: h[64] spilled, +40MB scratch traffic).
//     Weights via per-lane broadcast float4 global loads (L1-resident).
// ---------------------------------------------------------------------------

#define SCAN_ELEMS 1024

__global__ __launch_bounds__(256) void k_hist(const int* __restrict__ dst, int E,
        int* __restrict__ cnt_node, const int* __restrict__ batch, int N,
        int* __restrict__ cnt_graph) {
    int i = blockIdx.x * blockDim.x + threadIdx.x;
    if (i < E) atomicAdd(&cnt_node[dst[i]], 1);
    if (i < N) atomicAdd(&cnt_graph[batch[i]], 1);
}

__global__ __launch_bounds__(256) void k_scan1(const int* __restrict__ cnt, int n,
        int* __restrict__ rp, int* __restrict__ bsum) {
    __shared__ int sdata[256];
    int t = threadIdx.x;
    int base = blockIdx.x * SCAN_ELEMS + t * 4;
    int v0 = (base + 0 < n) ? cnt[base + 0] : 0;
    int v1 = (base + 1 < n) ? cnt[base + 1] : 0;
    int v2 = (base + 2 < n) ? cnt[base + 2] : 0;
    int v3 = (base + 3 < n) ? cnt[base + 3] : 0;
    int tsum = v0 + v1 + v2 + v3;
    sdata[t] = tsum;
    __syncthreads();
    for (int off = 1; off < 256; off <<= 1) {
        int val = (t >= off) ? sdata[t - off] : 0;
        __syncthreads();
        sdata[t] += val;
        __syncthreads();
    }
    int excl = sdata[t] - tsum;
    if (t == 255) bsum[blockIdx.x] = sdata[255];
    if (base + 0 < n) rp[base + 0] = excl;
    if (base + 1 < n) rp[base + 1] = excl + v0;
    if (base + 2 < n) rp[base + 2] = excl + v0 + v1;
    if (base + 3 < n) rp[base + 3] = excl + v0 + v1 + v2;
}

__global__ __launch_bounds__(128) void k_scan2(const int* __restrict__ bsum, int nb,
        int* __restrict__ boffs) {
    __shared__ int sd[128];
    int t = threadIdx.x;
    int v = (t < nb) ? bsum[t] : 0;
    sd[t] = v;
    __syncthreads();
    for (int off = 1; off < 128; off <<= 1) {
        int val = (t >= off) ? sd[t - off] : 0;
        __syncthreads();
        sd[t] += val;
        __syncthreads();
    }
    if (t < nb) boffs[t] = sd[t] - v;
}

__global__ __launch_bounds__(256) void k_scan3(int* __restrict__ rp, int n,
        const int* __restrict__ boffs, int E) {
    int i = blockIdx.x * blockDim.x + threadIdx.x;
    if (i < n) rp[i] += boffs[i / SCAN_ELEMS];
    if (i == 0) rp[n] = E;
}

__global__ __launch_bounds__(256) void k_fill(const int* __restrict__ src,
        const int* __restrict__ dst, int E, const int* __restrict__ rp,
        int* __restrict__ cursor, int* __restrict__ col) {
    int e = blockIdx.x * blockDim.x + threadIdx.x;
    if (e < E) {
        int d = dst[e];
        int pos = rp[d] + atomicAdd(&cursor[d], 1);
        col[pos] = src[e];
    }
}

// y = x @ W1a  (x: [N,11], W1a: [11,64]); weights in VGPRs, x via scalar loads
__global__ __launch_bounds__(256) void k_premm(const float* __restrict__ x,
        const float* __restrict__ W1a, float* __restrict__ y, int N) {
    int lane = threadIdx.x & 63, wv = threadIdx.x >> 6;
    float w[11];
#pragma unroll
    for (int k = 0; k < 11; ++k) w[k] = W1a[k * 64 + lane];
    int wg = blockIdx.x * 4 + wv, ws = gridDim.x * 4;
    for (int i = wg; i < N; i += ws) {
        float acc = 0.f;
#pragma unroll
        for (int k = 0; k < 11; ++k) acc = fmaf(x[i * 11 + k], w[k], acc);
        y[i * 64 + lane] = acc;
    }
}

// Gather: one wave per node, lane = channel. s = v_n + sum_j v_j.
// Folds previous-layer BN affine: h2 = a*s + b*(1+deg). 8-deep load ILP.
template <bool FIRST>
__global__ __launch_bounds__(256, 8) void k_gather(
        const float* __restrict__ vin, float* __restrict__ agg,
        const int* __restrict__ rp, const int* __restrict__ col,
        const float* __restrict__ ab_prev, int N) {
    int lane = threadIdx.x & 63, wv = threadIdx.x >> 6;
    int n = blockIdx.x * 4 + wv;
    if (n >= N) return;
    float a = 1.f, b = 0.f;
    if (!FIRST) { a = ab_prev[lane]; b = ab_prev[64 + lane]; }
    int start = rp[n], end = rp[n + 1];
    float s0 = vin[(size_t)n * 64 + lane];
    float s1 = 0.f, s2 = 0.f, s3 = 0.f, s4 = 0.f, s5 = 0.f, s6 = 0.f, s7 = 0.f;
    int e = start;
    for (; e + 8 <= end; e += 8) {
        int j0 = col[e + 0], j1 = col[e + 1], j2 = col[e + 2], j3 = col[e + 3];
        int j4 = col[e + 4], j5 = col[e + 5], j6 = col[e + 6], j7 = col[e + 7];
        s0 += vin[(size_t)j0 * 64 + lane];
        s1 += vin[(size_t)j1 * 64 + lane];
        s2 += vin[(size_t)j2 * 64 + lane];
        s3 += vin[(size_t)j3 * 64 + lane];
        s4 += vin[(size_t)j4 * 64 + lane];
        s5 += vin[(size_t)j5 * 64 + lane];
        s6 += vin[(size_t)j6 * 64 + lane];
        s7 += vin[(size_t)j7 * 64 + lane];
    }
    for (; e < end; ++e) s0 += vin[(size_t)col[e] * 64 + lane];
    float s = ((s0 + s1) + (s2 + s3)) + ((s4 + s5) + (s6 + s7));
    float h2 = FIRST ? s : fmaf(a, s, b * (float)(1 + end - start));
    agg[(size_t)n * 64 + lane] = h2;
}

// MLP: one block = one 64-node tile. k-chunked matvecs, no big local arrays.
template <bool FIRST>
__global__ __launch_bounds__(256, 4) void k_mlp(
        const float* __restrict__ agg, float* __restrict__ vout,
        const int* __restrict__ batch,
        const float* __restrict__ Wa, const float* __restrict__ ba,
        const float* __restrict__ Wb, const float* __restrict__ bb,
        float* __restrict__ Sg, float* __restrict__ bnpart,
        int N) {
    __shared__ float hb[64 * 64];
    float4* hb4 = (float4*)hb;
    const int tid = threadIdx.x;
    const int lane = tid & 63;
    const int wv = tid >> 6;
    const int n0 = blockIdx.x * 64;
    const int l15 = lane & 15;
    const int c0 = wv * 16;

    // ---- phase A: coalesced tile load -> LDS (swizzled) ----
    {
        const float4* a4 = (const float4*)(agg + (size_t)n0 * 64);
#pragma unroll
        for (int r = 0; r < 4; ++r) {
            int i = tid + r * 256;          // float4 index within tile
            int nt = i >> 4, q = i & 15;
            float4 v = make_float4(0.f, 0.f, 0.f, 0.f);
            if (n0 + nt < N) v = a4[i];
            hb4[nt * 16 + (q ^ (nt & 15))] = v;
        }
    }
    __syncthreads();

    float acc[16];

    if (!FIRST) {
        // ---- matvec1: t[c0+j] = relu(sum_k h[k]*Wa[k][c0+j] + ba[c0+j]) ----
        {
            float4 b4a = *(const float4*)(ba + c0);
            float4 b4b = *(const float4*)(ba + c0 + 4);
            float4 b4c = *(const float4*)(ba + c0 + 8);
            float4 b4d = *(const float4*)(ba + c0 + 12);
            acc[0] = b4a.x; acc[1] = b4a.y; acc[2] = b4a.z; acc[3] = b4a.w;
            acc[4] = b4b.x; acc[5] = b4b.y; acc[6] = b4b.z; acc[7] = b4b.w;
            acc[8] = b4c.x; acc[9] = b4c.y; acc[10] = b4c.z; acc[11] = b4c.w;
            acc[12] = b4d.x; acc[13] = b4d.y; acc[14] = b4d.z; acc[15] = b4d.w;
        }
        for (int kc = 0; kc < 4; ++kc) {
            float hq[16];
#pragma unroll
            for (int q4 = 0; q4 < 4; ++q4) {
                float4 hv = hb4[lane * 16 + ((kc * 4 + q4) ^ l15)];
                hq[q4 * 4 + 0] = hv.x; hq[q4 * 4 + 1] = hv.y;
                hq[q4 * 4 + 2] = hv.z; hq[q4 * 4 + 3] = hv.w;
            }
            const float* wbase = Wa + (size_t)(kc * 16) * 64 + c0;
#pragma unroll
            for (int kk = 0; kk < 16; ++kk) {
                float4 w0 = *(const float4*)(wbase + kk * 64 + 0);
                float4 w1 = *(const float4*)(wbase + kk * 64 + 4);
                float4 w2 = *(const float4*)(wbase + kk * 64 + 8);
                float4 w3 = *(const float4*)(wbase + kk * 64 + 12);
                float hk = hq[kk];
                acc[0] = fmaf(hk, w0.x, acc[0]);  acc[1] = fmaf(hk, w0.y, acc[1]);
                acc[2] = fmaf(hk, w0.z, acc[2]);  acc[3] = fmaf(hk, w0.w, acc[3]);
                acc[4] = fmaf(hk, w1.x, acc[4]);  acc[5] = fmaf(hk, w1.y, acc[5]);
                acc[6] = fmaf(hk, w1.z, acc[6]);  acc[7] = fmaf(hk, w1.w, acc[7]);
                acc[8] = fmaf(hk, w2.x, acc[8]);  acc[9] = fmaf(hk, w2.y, acc[9]);
                acc[10] = fmaf(hk, w2.z, acc[10]); acc[11] = fmaf(hk, w2.w, acc[11]);
                acc[12] = fmaf(hk, w3.x, acc[12]); acc[13] = fmaf(hk, w3.y, acc[13]);
                acc[14] = fmaf(hk, w3.z, acc[14]); acc[15] = fmaf(hk, w3.w, acc[15]);
            }
        }
        __syncthreads();   // everyone done reading h from hb
#pragma unroll
        for (int j4 = 0; j4 < 4; ++j4) {
            int q = wv * 4 + j4;
            hb4[lane * 16 + (q ^ l15)] = make_float4(
                fmaxf(acc[j4 * 4 + 0], 0.f), fmaxf(acc[j4 * 4 + 1], 0.f),
                fmaxf(acc[j4 * 4 + 2], 0.f), fmaxf(acc[j4 * 4 + 3], 0.f));
        }
        __syncthreads();
    }

    // ---- matvec2: v[c0+j] = relu(sum_k t[k]*Wb[k][c0+j] + bb[c0+j]) ----
    // FIRST: t[k] = relu(h[k] + ba[k]) fused per chunk (W1a folded upstream).
    {
        float4 b4a = *(const float4*)(bb + c0);
        float4 b4b = *(const float4*)(bb + c0 + 4);
        float4 b4c = *(const float4*)(bb + c0 + 8);
        float4 b4d = *(const float4*)(bb + c0 + 12);
        acc[0] = b4a.x; acc[1] = b4a.y; acc[2] = b4a.z; acc[3] = b4a.w;
        acc[4] = b4b.x; acc[5] = b4b.y; acc[6] = b4b.z; acc[7] = b4b.w;
        acc[8] = b4c.x; acc[9] = b4c.y; acc[10] = b4c.z; acc[11] = b4c.w;
        acc[12] = b4d.x; acc[13] = b4d.y; acc[14] = b4d.z; acc[15] = b4d.w;
    }
    for (int kc = 0; kc < 4; ++kc) {
        float hq[16];
#pragma unroll
        for (int q4 = 0; q4 < 4; ++q4) {
            float4 hv = hb4[lane * 16 + ((kc * 4 + q4) ^ l15)];
            hq[q4 * 4 + 0] = hv.x; hq[q4 * 4 + 1] = hv.y;
            hq[q4 * 4 + 2] = hv.z; hq[q4 * 4 + 3] = hv.w;
        }
        if (FIRST) {
#pragma unroll
            for (int q4 = 0; q4 < 4; ++q4) {
                float4 bav = *(const float4*)(ba + kc * 16 + q4 * 4);
                hq[q4 * 4 + 0] = fmaxf(hq[q4 * 4 + 0] + bav.x, 0.f);
                hq[q4 * 4 + 1] = fmaxf(hq[q4 * 4 + 1] + bav.y, 0.f);
                hq[q4 * 4 + 2] = fmaxf(hq[q4 * 4 + 2] + bav.z, 0.f);
                hq[q4 * 4 + 3] = fmaxf(hq[q4 * 4 + 3] + bav.w, 0.f);
            }
        }
        const float* wbase = Wb + (size_t)(kc * 16) * 64 + c0;
#pragma unroll
        for (int kk = 0; kk < 16; ++kk) {
            float4 w0 = *(const float4*)(wbase + kk * 64 + 0);
            float4 w1 = *(const float4*)(wbase + kk * 64 + 4);
            float4 w2 = *(const float4*)(wbase + kk * 64 + 8);
            float4 w3 = *(const float4*)(wbase + kk * 64 + 12);
            float hk = hq[kk];
            acc[0] = fmaf(hk, w0.x, acc[0]);  acc[1] = fmaf(hk, w0.y, acc[1]);
            acc[2] = fmaf(hk, w0.z, acc[2]);  acc[3] = fmaf(hk, w0.w, acc[3]);
            acc[4] = fmaf(hk, w1.x, acc[4]);  acc[5] = fmaf(hk, w1.y, acc[5]);
            acc[6] = fmaf(hk, w1.z, acc[6]);  acc[7] = fmaf(hk, w1.w, acc[7]);
            acc[8] = fmaf(hk, w2.x, acc[8]);  acc[9] = fmaf(hk, w2.y, acc[9]);
            acc[10] = fmaf(hk, w2.z, acc[10]); acc[11] = fmaf(hk, w2.w, acc[11]);
            acc[12] = fmaf(hk, w3.x, acc[12]); acc[13] = fmaf(hk, w3.y, acc[13]);
            acc[14] = fmaf(hk, w3.z, acc[14]); acc[15] = fmaf(hk, w3.w, acc[15]);
        }
    }
    __syncthreads();   // everyone done reading hb
    {
#pragma unroll
        for (int j4 = 0; j4 < 4; ++j4) {
            int q = wv * 4 + j4;
            hb4[lane * 16 + (q ^ l15)] = make_float4(
                fmaxf(acc[j4 * 4 + 0], 0.f), fmaxf(acc[j4 * 4 + 1], 0.f),
                fmaxf(acc[j4 * 4 + 2], 0.f), fmaxf(acc[j4 * 4 + 3], 0.f));
        }
    }
    __syncthreads();

    // ---- phase C: store + BN stats + graph pooling ----
    {
        int q = lane & 15;          // channel quad
        int ng = lane >> 4;         // node subgroup
        float4 bs = make_float4(0, 0, 0, 0), bq = make_float4(0, 0, 0, 0);
        float4 pacc = make_float4(0, 0, 0, 0);
        int curg = -1;
#pragma unroll
        for (int s2 = 0; s2 < 4; ++s2) {
            int nt = wv * 16 + s2 * 4 + ng;
            int n = n0 + nt;
            if (n < N) {
                float4 v = hb4[nt * 16 + (q ^ (nt & 15))];
                *(float4*)(vout + (size_t)n * 64 + q * 4) = v;
                bs.x += v.x; bs.y += v.y; bs.z += v.z; bs.w += v.w;
                bq.x += v.x * v.x; bq.y += v.y * v.y;
                bq.z += v.z * v.z; bq.w += v.w * v.w;
                int g = batch[n];
                if (g != curg) {
                    if (curg >= 0) {
                        atomicAdd(&Sg[curg * 64 + q * 4 + 0], pacc.x);
                        atomicAdd(&Sg[curg * 64 + q * 4 + 1], pacc.y);
                        atomicAdd(&Sg[curg * 64 + q * 4 + 2], pacc.z);
                        atomicAdd(&Sg[curg * 64 + q * 4 + 3], pacc.w);
                    }
                    curg = g;
                    pacc = make_float4(0, 0, 0, 0);
                }
                pacc.x += v.x; pacc.y += v.y; pacc.z += v.z; pacc.w += v.w;
            }
        }
        if (curg >= 0) {
            atomicAdd(&Sg[curg * 64 + q * 4 + 0], pacc.x);
            atomicAdd(&Sg[curg * 64 + q * 4 + 1], pacc.y);
            atomicAdd(&Sg[curg * 64 + q * 4 + 2], pacc.z);
            atomicAdd(&Sg[curg * 64 + q * 4 + 3], pacc.w);
        }
#pragma unroll
        for (int off = 16; off < 64; off <<= 1) {
            bs.x += __shfl_xor(bs.x, off); bs.y += __shfl_xor(bs.y, off);
            bs.z += __shfl_xor(bs.z, off); bs.w += __shfl_xor(bs.w, off);
            bq.x += __shfl_xor(bq.x, off); bq.y += __shfl_xor(bq.y, off);
            bq.z += __shfl_xor(bq.z, off); bq.w += __shfl_xor(bq.w, off);
        }
        if (ng == 0) {
            float* bkt = bnpart + (blockIdx.x & 31) * 128;
            atomicAdd(&bkt[q * 4 + 0], bs.x);
            atomicAdd(&bkt[q * 4 + 1], bs.y);
            atomicAdd(&bkt[q * 4 + 2], bs.z);
            atomicAdd(&bkt[q * 4 + 3], bs.w);
            atomicAdd(&bkt[64 + q * 4 + 0], bq.x);
            atomicAdd(&bkt[64 + q * 4 + 1], bq.y);
            atomicAdd(&bkt[64 + q * 4 + 2], bq.z);
            atomicAdd(&bkt[64 + q * 4 + 3], bq.w);
        }
    }
}

__global__ void k_bnstat(const float* __restrict__ bnpart,
        const float* __restrict__ gamma, const float* __restrict__ beta,
        float* __restrict__ a, float* __restrict__ b, int N) {
    int c = threadIdx.x;  // 64 threads
    float s = 0.f, q = 0.f;
    for (int i = 0; i < 32; ++i) { s += bnpart[i * 128 + c]; q += bnpart[i * 128 + 64 + c]; }
    float invN = 1.0f / (float)N;
    float mu = s * invN;
    float var = q * invN - mu * mu;
    float ac = gamma[c] * rsqrtf(var + 1e-5f);
    a[c] = ac;
    b[c] = beta[c] - mu * ac;
}

// Head: z[g,320] = concat_l (a_l*S_l[g] + b_l*cnt[g]); out = relu(z@fc1+b)@fc2+b
__global__ __launch_bounds__(256) void k_final(
        const float* __restrict__ S, const float* __restrict__ ab,
        const int* __restrict__ cntg,
        const float* __restrict__ fc1W, const float* __restrict__ fc1b,
        const float* __restrict__ fc2W, const float* __restrict__ fc2b,
        float* __restrict__ out, int G) {
    __shared__ float zbuf[4][320];
    int tid = threadIdx.x;
    int lane = tid & 63, wv = tid >> 6;
    int g = blockIdx.x * 4 + wv;
    if (g >= G) return;
    float cf = (float)cntg[g];
#pragma unroll
    for (int l = 0; l < 5; ++l) {
        float a = ab[l * 128 + lane];
        float b = ab[l * 128 + 64 + lane];
        zbuf[wv][l * 64 + lane] = a * S[((size_t)l * G + g) * 64 + lane] + b * cf;
    }
    float acc = fc1b[lane];
    for (int k = 0; k < 320; ++k) acc += zbuf[wv][k] * fc1W[k * 64 + lane];
    float t = fmaxf(acc, 0.f);
    float r = t * fc2W[lane];
#pragma unroll
    for (int off = 32; off >= 1; off >>= 1) r += __shfl_xor(r, off);
    if (lane == 0) out[g] = r + fc2b[0];
}

extern "C" void kernel_launch(void* const* d_in, const int* in_sizes, int n_in,
                              void* d_out, int out_size, void* d_ws, size_t ws_size,
                              hipStream_t stream) {
    const float* x    = (const float*)d_in[0];
    const int*   ei   = (const int*)d_in[1];
    const int*   batch= (const int*)d_in[2];
    const float* W1a  = (const float*)d_in[3];
    const float* b1a  = (const float*)d_in[4];
    const float* W1b  = (const float*)d_in[5];
    const float* b1b  = (const float*)d_in[6];
    const float* Wa   = (const float*)d_in[7];
    const float* ba   = (const float*)d_in[8];
    const float* Wb   = (const float*)d_in[9];
    const float* bb   = (const float*)d_in[10];
    const float* gamma= (const float*)d_in[11];
    const float* beta = (const float*)d_in[12];
    const float* fc1W = (const float*)d_in[13];
    const float* fc1b = (const float*)d_in[14];
    const float* fc2W = (const float*)d_in[15];
    const float* fc2b = (const float*)d_in[16];

    const int N = in_sizes[2];
    const int E = in_sizes[1] / 2;
    const int G = out_size;
    const int* srcp = ei;
    const int* dstp = ei + E;

    char* p = (char*)d_ws;
    auto alloc = [&](size_t bytes) {
        char* r = p;
        p += (bytes + 255) & ~size_t(255);
        return r;
    };
    float* B0     = (float*)alloc((size_t)N * 64 * 4);
    float* B1     = (float*)alloc((size_t)N * 64 * 4);
    int*   col    = (int*)  alloc((size_t)E * 4);
    int*   rp     = (int*)  alloc((size_t)(N + 1) * 4);
    int*   cntn   = (int*)  alloc((size_t)N * 4);
    int*   cursor = (int*)  alloc((size_t)N * 4);
    int*   bsum   = (int*)  alloc(512);
    int*   boffs  = (int*)  alloc(512);
    int*   cntg   = (int*)  alloc((size_t)G * 4);
    float* S      = (float*)alloc((size_t)5 * G * 64 * 4);
    float* bnpart = (float*)alloc((size_t)5 * 32 * 128 * 4);
    float* ab     = (float*)alloc(5 * 128 * 4);

    hipMemsetAsync(cntn,   0, (size_t)N * 4, stream);
    hipMemsetAsync(cursor, 0, (size_t)N * 4, stream);
    hipMemsetAsync(cntg,   0, (size_t)G * 4, stream);
    hipMemsetAsync(S,      0, (size_t)5 * G * 64 * 4, stream);
    hipMemsetAsync(bnpart, 0, (size_t)5 * 32 * 128 * 4, stream);

    int nb_e = (E + 255) / 256;
    int nb_scan = (N + SCAN_ELEMS - 1) / SCAN_ELEMS;
    k_hist<<<nb_e, 256, 0, stream>>>(dstp, E, cntn, batch, N, cntg);
    k_scan1<<<nb_scan, 256, 0, stream>>>(cntn, N, rp, bsum);
    k_scan2<<<1, 128, 0, stream>>>(bsum, nb_scan, boffs);
    k_scan3<<<(N + 255) / 256, 256, 0, stream>>>(rp, N, boffs, E);
    k_fill<<<nb_e, 256, 0, stream>>>(srcp, dstp, E, rp, cursor, col);

    k_premm<<<512, 256, 0, stream>>>(x, W1a, B0, N);

    int nb_node = (N + 3) / 4;
    int nb_tile = (N + 63) / 64;

    // Layer 1 (W1a folded into k_premm): gather B0 -> B1, mlp B1 -> B0
    k_gather<true><<<nb_node, 256, 0, stream>>>(B0, B1, rp, col, nullptr, N);
    k_mlp<true><<<nb_tile, 256, 0, stream>>>(B1, B0, batch,
        nullptr, b1a, W1b, b1b, S, bnpart, N);
    k_bnstat<<<1, 64, 0, stream>>>(bnpart, gamma, beta, ab, ab + 64, N);

    for (int l = 0; l < 4; ++l) {
        k_gather<false><<<nb_node, 256, 0, stream>>>(B0, B1, rp, col,
            ab + l * 128, N);
        k_mlp<false><<<nb_tile, 256, 0, stream>>>(B1, B0, batch,
            Wa + l * 4096, ba + l * 64, Wb + l * 4096, bb + l * 64,
            S + (size_t)(l + 1) * G * 64,
            bnpart + (size_t)(l + 1) * 32 * 128, N);
        k_bnstat<<<1, 64, 0, stream>>>(
            bnpart + (size_t)(l + 1) * 32 * 128,
            gamma + (l + 1) * 64, beta + (l + 1) * 64,
            ab + (l + 1) * 128, ab + (l + 1) * 128 + 64, N);
    }

    k_final<<<(G + 3) / 4, 256, 0, stream>>>(S, ab, cntg, fc1W, fc1b, fc2W, fc2b,
                                             (float*)d_out, G);
}

// Round 5
// 974.792 us; speedup vs baseline: 1.5631x; 1.3472x over previous
//
#include <hip/hip_runtime.h>

// ---------------------------------------------------------------------------
// GIN (5 layers) + BN + graph pooling + MLP head, fp32.
// R5: k_mlp weight reads forced onto the SCALAR pipe via
//     readfirstlane(wv) -> provably-uniform addresses -> s_load into SGPRs
//     (v_fmac vdst, s, v). R4 was latency-bound: non-uniform float4 weight
//     loads with only ~4 in flight (VGPR=36) -> 14% VALUBusy. Also: pooling
//     atomics reduced 4x via wave-uniform same-graph fast path (shfl_xor
//     reduction across node subgroups) -> WRITE_SIZE 65.6 -> ~30 MB.
// ---------------------------------------------------------------------------

#define SCAN_ELEMS 1024

__global__ __launch_bounds__(256) void k_hist(const int* __restrict__ dst, int E,
        int* __restrict__ cnt_node, const int* __restrict__ batch, int N,
        int* __restrict__ cnt_graph) {
    int i = blockIdx.x * blockDim.x + threadIdx.x;
    if (i < E) atomicAdd(&cnt_node[dst[i]], 1);
    if (i < N) atomicAdd(&cnt_graph[batch[i]], 1);
}

__global__ __launch_bounds__(256) void k_scan1(const int* __restrict__ cnt, int n,
        int* __restrict__ rp, int* __restrict__ bsum) {
    __shared__ int sdata[256];
    int t = threadIdx.x;
    int base = blockIdx.x * SCAN_ELEMS + t * 4;
    int v0 = (base + 0 < n) ? cnt[base + 0] : 0;
    int v1 = (base + 1 < n) ? cnt[base + 1] : 0;
    int v2 = (base + 2 < n) ? cnt[base + 2] : 0;
    int v3 = (base + 3 < n) ? cnt[base + 3] : 0;
    int tsum = v0 + v1 + v2 + v3;
    sdata[t] = tsum;
    __syncthreads();
    for (int off = 1; off < 256; off <<= 1) {
        int val = (t >= off) ? sdata[t - off] : 0;
        __syncthreads();
        sdata[t] += val;
        __syncthreads();
    }
    int excl = sdata[t] - tsum;
    if (t == 255) bsum[blockIdx.x] = sdata[255];
    if (base + 0 < n) rp[base + 0] = excl;
    if (base + 1 < n) rp[base + 1] = excl + v0;
    if (base + 2 < n) rp[base + 2] = excl + v0 + v1;
    if (base + 3 < n) rp[base + 3] = excl + v0 + v1 + v2;
}

__global__ __launch_bounds__(128) void k_scan2(const int* __restrict__ bsum, int nb,
        int* __restrict__ boffs) {
    __shared__ int sd[128];
    int t = threadIdx.x;
    int v = (t < nb) ? bsum[t] : 0;
    sd[t] = v;
    __syncthreads();
    for (int off = 1; off < 128; off <<= 1) {
        int val = (t >= off) ? sd[t - off] : 0;
        __syncthreads();
        sd[t] += val;
        __syncthreads();
    }
    if (t < nb) boffs[t] = sd[t] - v;
}

__global__ __launch_bounds__(256) void k_scan3(int* __restrict__ rp, int n,
        const int* __restrict__ boffs, int E) {
    int i = blockIdx.x * blockDim.x + threadIdx.x;
    if (i < n) rp[i] += boffs[i / SCAN_ELEMS];
    if (i == 0) rp[n] = E;
}

__global__ __launch_bounds__(256) void k_fill(const int* __restrict__ src,
        const int* __restrict__ dst, int E, const int* __restrict__ rp,
        int* __restrict__ cursor, int* __restrict__ col) {
    int e = blockIdx.x * blockDim.x + threadIdx.x;
    if (e < E) {
        int d = dst[e];
        int pos = rp[d] + atomicAdd(&cursor[d], 1);
        col[pos] = src[e];
    }
}

// y = x @ W1a  (x: [N,11], W1a: [11,64]); weights in VGPRs, x via scalar loads
__global__ __launch_bounds__(256) void k_premm(const float* __restrict__ x,
        const float* __restrict__ W1a, float* __restrict__ y, int N) {
    int lane = threadIdx.x & 63, wv = threadIdx.x >> 6;
    float w[11];
#pragma unroll
    for (int k = 0; k < 11; ++k) w[k] = W1a[k * 64 + lane];
    int wg = blockIdx.x * 4 + wv, ws = gridDim.x * 4;
    for (int i = wg; i < N; i += ws) {
        float acc = 0.f;
#pragma unroll
        for (int k = 0; k < 11; ++k) acc = fmaf(x[i * 11 + k], w[k], acc);
        y[i * 64 + lane] = acc;
    }
}

// Gather: one wave per node, lane = channel. s = v_n + sum_j v_j.
// Folds previous-layer BN affine: h2 = a*s + b*(1+deg). 8-deep load ILP.
template <bool FIRST>
__global__ __launch_bounds__(256, 8) void k_gather(
        const float* __restrict__ vin, float* __restrict__ agg,
        const int* __restrict__ rp, const int* __restrict__ col,
        const float* __restrict__ ab_prev, int N) {
    int lane = threadIdx.x & 63, wv = threadIdx.x >> 6;
    int n = blockIdx.x * 4 + wv;
    if (n >= N) return;
    float a = 1.f, b = 0.f;
    if (!FIRST) { a = ab_prev[lane]; b = ab_prev[64 + lane]; }
    int start = rp[n], end = rp[n + 1];
    float s0 = vin[(size_t)n * 64 + lane];
    float s1 = 0.f, s2 = 0.f, s3 = 0.f, s4 = 0.f, s5 = 0.f, s6 = 0.f, s7 = 0.f;
    int e = start;
    for (; e + 8 <= end; e += 8) {
        int j0 = col[e + 0], j1 = col[e + 1], j2 = col[e + 2], j3 = col[e + 3];
        int j4 = col[e + 4], j5 = col[e + 5], j6 = col[e + 6], j7 = col[e + 7];
        s0 += vin[(size_t)j0 * 64 + lane];
        s1 += vin[(size_t)j1 * 64 + lane];
        s2 += vin[(size_t)j2 * 64 + lane];
        s3 += vin[(size_t)j3 * 64 + lane];
        s4 += vin[(size_t)j4 * 64 + lane];
        s5 += vin[(size_t)j5 * 64 + lane];
        s6 += vin[(size_t)j6 * 64 + lane];
        s7 += vin[(size_t)j7 * 64 + lane];
    }
    for (; e < end; ++e) s0 += vin[(size_t)col[e] * 64 + lane];
    float s = ((s0 + s1) + (s2 + s3)) + ((s4 + s5) + (s6 + s7));
    float h2 = FIRST ? s : fmaf(a, s, b * (float)(1 + end - start));
    agg[(size_t)n * 64 + lane] = h2;
}

// MLP: one block = one 64-node tile. k-chunked matvecs; weights via the
// scalar pipe (readfirstlane-uniform addresses -> s_load -> SGPR operands).
template <bool FIRST>
__global__ __launch_bounds__(256, 4) void k_mlp(
        const float* __restrict__ agg, float* __restrict__ vout,
        const int* __restrict__ batch,
        const float* __restrict__ Wa, const float* __restrict__ ba,
        const float* __restrict__ Wb, const float* __restrict__ bb,
        float* __restrict__ Sg, float* __restrict__ bnpart,
        int N) {
    __shared__ float hb[64 * 64];
    float4* hb4 = (float4*)hb;
    const int tid = threadIdx.x;
    const int lane = tid & 63;
    const int wv = tid >> 6;
    const int n0 = blockIdx.x * 64;
    const int l15 = lane & 15;
    // wave-uniform channel base, provably uniform -> weight reads use s_load
    const int c0 = __builtin_amdgcn_readfirstlane(wv) * 16;

    // ---- phase A: coalesced tile load -> LDS (swizzled) ----
    {
        const float4* a4 = (const float4*)(agg + (size_t)n0 * 64);
#pragma unroll
        for (int r = 0; r < 4; ++r) {
            int i = tid + r * 256;          // float4 index within tile
            int nt = i >> 4, q = i & 15;
            float4 v = make_float4(0.f, 0.f, 0.f, 0.f);
            if (n0 + nt < N) v = a4[i];
            hb4[nt * 16 + (q ^ (nt & 15))] = v;
        }
    }
    __syncthreads();

    float acc[16];

    if (!FIRST) {
        // ---- matvec1: t[c0+j] = relu(sum_k h[k]*Wa[k][c0+j] + ba[c0+j]) ----
#pragma unroll
        for (int j = 0; j < 16; ++j) acc[j] = ba[c0 + j];
        for (int kc = 0; kc < 4; ++kc) {
            float hq[16];
#pragma unroll
            for (int q4 = 0; q4 < 4; ++q4) {
                float4 hv = hb4[lane * 16 + ((kc * 4 + q4) ^ l15)];
                hq[q4 * 4 + 0] = hv.x; hq[q4 * 4 + 1] = hv.y;
                hq[q4 * 4 + 2] = hv.z; hq[q4 * 4 + 3] = hv.w;
            }
            const float* wbase = Wa + (size_t)(kc * 16) * 64 + c0;   // uniform
#pragma unroll
            for (int kk = 0; kk < 16; ++kk) {
                float w[16];
#pragma unroll
                for (int j = 0; j < 16; ++j) w[j] = wbase[kk * 64 + j];  // s_load
                float hk = hq[kk];
#pragma unroll
                for (int j = 0; j < 16; ++j) acc[j] = fmaf(hk, w[j], acc[j]);
            }
        }
        __syncthreads();   // everyone done reading h from hb
#pragma unroll
        for (int j4 = 0; j4 < 4; ++j4) {
            int q = wv * 4 + j4;
            hb4[lane * 16 + (q ^ l15)] = make_float4(
                fmaxf(acc[j4 * 4 + 0], 0.f), fmaxf(acc[j4 * 4 + 1], 0.f),
                fmaxf(acc[j4 * 4 + 2], 0.f), fmaxf(acc[j4 * 4 + 3], 0.f));
        }
        __syncthreads();
    }

    // ---- matvec2: v[c0+j] = relu(sum_k t[k]*Wb[k][c0+j] + bb[c0+j]) ----
    // FIRST: t[k] = relu(h[k] + ba[k]) fused per chunk (W1a folded upstream).
#pragma unroll
    for (int j = 0; j < 16; ++j) acc[j] = bb[c0 + j];
    for (int kc = 0; kc < 4; ++kc) {
        float hq[16];
#pragma unroll
        for (int q4 = 0; q4 < 4; ++q4) {
            float4 hv = hb4[lane * 16 + ((kc * 4 + q4) ^ l15)];
            hq[q4 * 4 + 0] = hv.x; hq[q4 * 4 + 1] = hv.y;
            hq[q4 * 4 + 2] = hv.z; hq[q4 * 4 + 3] = hv.w;
        }
        if (FIRST) {
#pragma unroll
            for (int kk = 0; kk < 16; ++kk)
                hq[kk] = fmaxf(hq[kk] + ba[kc * 16 + kk], 0.f);
        }
        const float* wbase = Wb + (size_t)(kc * 16) * 64 + c0;       // uniform
#pragma unroll
        for (int kk = 0; kk < 16; ++kk) {
            float w[16];
#pragma unroll
            for (int j = 0; j < 16; ++j) w[j] = wbase[kk * 64 + j];  // s_load
            float hk = hq[kk];
#pragma unroll
            for (int j = 0; j < 16; ++j) acc[j] = fmaf(hk, w[j], acc[j]);
        }
    }
    __syncthreads();   // everyone done reading hb
    {
#pragma unroll
        for (int j4 = 0; j4 < 4; ++j4) {
            int q = wv * 4 + j4;
            hb4[lane * 16 + (q ^ l15)] = make_float4(
                fmaxf(acc[j4 * 4 + 0], 0.f), fmaxf(acc[j4 * 4 + 1], 0.f),
                fmaxf(acc[j4 * 4 + 2], 0.f), fmaxf(acc[j4 * 4 + 3], 0.f));
        }
    }
    __syncthreads();

    // ---- phase C: store + BN stats + graph pooling ----
    {
        int q = lane & 15;          // channel quad
        int ng = lane >> 4;         // node subgroup
        int base_nt = wv * 16;
        float4 bs = make_float4(0, 0, 0, 0), bq = make_float4(0, 0, 0, 0);

        bool full = (n0 + base_nt + 15) < N;            // wave-uniform
        int gf = 0, gl = -1;
        if (full) { gf = batch[n0 + base_nt]; gl = batch[n0 + base_nt + 15]; }

        if (full && gf == gl) {
            // fast path: whole 16-node group in one graph
            float4 pacc = make_float4(0, 0, 0, 0);
#pragma unroll
            for (int s2 = 0; s2 < 4; ++s2) {
                int nt = base_nt + s2 * 4 + ng;
                float4 v = hb4[nt * 16 + (q ^ (nt & 15))];
                *(float4*)(vout + (size_t)(n0 + nt) * 64 + q * 4) = v;
                bs.x += v.x; bs.y += v.y; bs.z += v.z; bs.w += v.w;
                bq.x += v.x * v.x; bq.y += v.y * v.y;
                bq.z += v.z * v.z; bq.w += v.w * v.w;
                pacc.x += v.x; pacc.y += v.y; pacc.z += v.z; pacc.w += v.w;
            }
#pragma unroll
            for (int off = 16; off < 64; off <<= 1) {
                pacc.x += __shfl_xor(pacc.x, off); pacc.y += __shfl_xor(pacc.y, off);
                pacc.z += __shfl_xor(pacc.z, off); pacc.w += __shfl_xor(pacc.w, off);
            }
            if (ng == 0) {
                atomicAdd(&Sg[gf * 64 + q * 4 + 0], pacc.x);
                atomicAdd(&Sg[gf * 64 + q * 4 + 1], pacc.y);
                atomicAdd(&Sg[gf * 64 + q * 4 + 2], pacc.z);
                atomicAdd(&Sg[gf * 64 + q * 4 + 3], pacc.w);
            }
        } else {
            // slow path: graph boundary inside the group (or tile tail)
            float4 pacc = make_float4(0, 0, 0, 0);
            int curg = -1;
#pragma unroll
            for (int s2 = 0; s2 < 4; ++s2) {
                int nt = base_nt + s2 * 4 + ng;
                int n = n0 + nt;
                if (n < N) {
                    float4 v = hb4[nt * 16 + (q ^ (nt & 15))];
                    *(float4*)(vout + (size_t)n * 64 + q * 4) = v;
                    bs.x += v.x; bs.y += v.y; bs.z += v.z; bs.w += v.w;
                    bq.x += v.x * v.x; bq.y += v.y * v.y;
                    bq.z += v.z * v.z; bq.w += v.w * v.w;
                    int g = batch[n];
                    if (g != curg) {
                        if (curg >= 0) {
                            atomicAdd(&Sg[curg * 64 + q * 4 + 0], pacc.x);
                            atomicAdd(&Sg[curg * 64 + q * 4 + 1], pacc.y);
                            atomicAdd(&Sg[curg * 64 + q * 4 + 2], pacc.z);
                            atomicAdd(&Sg[curg * 64 + q * 4 + 3], pacc.w);
                        }
                        curg = g;
                        pacc = make_float4(0, 0, 0, 0);
                    }
                    pacc.x += v.x; pacc.y += v.y; pacc.z += v.z; pacc.w += v.w;
                }
            }
            if (curg >= 0) {
                atomicAdd(&Sg[curg * 64 + q * 4 + 0], pacc.x);
                atomicAdd(&Sg[curg * 64 + q * 4 + 1], pacc.y);
                atomicAdd(&Sg[curg * 64 + q * 4 + 2], pacc.z);
                atomicAdd(&Sg[curg * 64 + q * 4 + 3], pacc.w);
            }
        }
#pragma unroll
        for (int off = 16; off < 64; off <<= 1) {
            bs.x += __shfl_xor(bs.x, off); bs.y += __shfl_xor(bs.y, off);
            bs.z += __shfl_xor(bs.z, off); bs.w += __shfl_xor(bs.w, off);
            bq.x += __shfl_xor(bq.x, off); bq.y += __shfl_xor(bq.y, off);
            bq.z += __shfl_xor(bq.z, off); bq.w += __shfl_xor(bq.w, off);
        }
        if (ng == 0) {
            float* bkt = bnpart + (blockIdx.x & 31) * 128;
            atomicAdd(&bkt[q * 4 + 0], bs.x);
            atomicAdd(&bkt[q * 4 + 1], bs.y);
            atomicAdd(&bkt[q * 4 + 2], bs.z);
            atomicAdd(&bkt[q * 4 + 3], bs.w);
            atomicAdd(&bkt[64 + q * 4 + 0], bq.x);
            atomicAdd(&bkt[64 + q * 4 + 1], bq.y);
            atomicAdd(&bkt[64 + q * 4 + 2], bq.z);
            atomicAdd(&bkt[64 + q * 4 + 3], bq.w);
        }
    }
}

__global__ void k_bnstat(const float* __restrict__ bnpart,
        const float* __restrict__ gamma, const float* __restrict__ beta,
        float* __restrict__ a, float* __restrict__ b, int N) {
    int c = threadIdx.x;  // 64 threads
    float s = 0.f, q = 0.f;
    for (int i = 0; i < 32; ++i) { s += bnpart[i * 128 + c]; q += bnpart[i * 128 + 64 + c]; }
    float invN = 1.0f / (float)N;
    float mu = s * invN;
    float var = q * invN - mu * mu;
    float ac = gamma[c] * rsqrtf(var + 1e-5f);
    a[c] = ac;
    b[c] = beta[c] - mu * ac;
}

// Head: z[g,320] = concat_l (a_l*S_l[g] + b_l*cnt[g]); out = relu(z@fc1+b)@fc2+b
__global__ __launch_bounds__(256) void k_final(
        const float* __restrict__ S, const float* __restrict__ ab,
        const int* __restrict__ cntg,
        const float* __restrict__ fc1W, const float* __restrict__ fc1b,
        const float* __restrict__ fc2W, const float* __restrict__ fc2b,
        float* __restrict__ out, int G) {
    __shared__ float zbuf[4][320];
    int tid = threadIdx.x;
    int lane = tid & 63, wv = tid >> 6;
    int g = blockIdx.x * 4 + wv;
    if (g >= G) return;
    float cf = (float)cntg[g];
#pragma unroll
    for (int l = 0; l < 5; ++l) {
        float a = ab[l * 128 + lane];
        float b = ab[l * 128 + 64 + lane];
        zbuf[wv][l * 64 + lane] = a * S[((size_t)l * G + g) * 64 + lane] + b * cf;
    }
    float acc = fc1b[lane];
    for (int k = 0; k < 320; ++k) acc += zbuf[wv][k] * fc1W[k * 64 + lane];
    float t = fmaxf(acc, 0.f);
    float r = t * fc2W[lane];
#pragma unroll
    for (int off = 32; off >= 1; off >>= 1) r += __shfl_xor(r, off);
    if (lane == 0) out[g] = r + fc2b[0];
}

extern "C" void kernel_launch(void* const* d_in, const int* in_sizes, int n_in,
                              void* d_out, int out_size, void* d_ws, size_t ws_size,
                              hipStream_t stream) {
    const float* x    = (const float*)d_in[0];
    const int*   ei   = (const int*)d_in[1];
    const int*   batch= (const int*)d_in[2];
    const float* W1a  = (const float*)d_in[3];
    const float* b1a  = (const float*)d_in[4];
    const float* W1b  = (const float*)d_in[5];
    const float* b1b  = (const float*)d_in[6];
    const float* Wa   = (const float*)d_in[7];
    const float* ba   = (const float*)d_in[8];
    const float* Wb   = (const float*)d_in[9];
    const float* bb   = (const float*)d_in[10];
    const float* gamma= (const float*)d_in[11];
    const float* beta = (const float*)d_in[12];
    const float* fc1W = (const float*)d_in[13];
    const float* fc1b = (const float*)d_in[14];
    const float* fc2W = (const float*)d_in[15];
    const float* fc2b = (const float*)d_in[16];

    const int N = in_sizes[2];
    const int E = in_sizes[1] / 2;
    const int G = out_size;
    const int* srcp = ei;
    const int* dstp = ei + E;

    char* p = (char*)d_ws;
    auto alloc = [&](size_t bytes) {
        char* r = p;
        p += (bytes + 255) & ~size_t(255);
        return r;
    };
    float* B0     = (float*)alloc((size_t)N * 64 * 4);
    float* B1     = (float*)alloc((size_t)N * 64 * 4);
    int*   col    = (int*)  alloc((size_t)E * 4);
    int*   rp     = (int*)  alloc((size_t)(N + 1) * 4);
    int*   cntn   = (int*)  alloc((size_t)N * 4);
    int*   cursor = (int*)  alloc((size_t)N * 4);
    int*   bsum   = (int*)  alloc(512);
    int*   boffs  = (int*)  alloc(512);
    int*   cntg   = (int*)  alloc((size_t)G * 4);
    float* S      = (float*)alloc((size_t)5 * G * 64 * 4);
    float* bnpart = (float*)alloc((size_t)5 * 32 * 128 * 4);
    float* ab     = (float*)alloc(5 * 128 * 4);

    hipMemsetAsync(cntn,   0, (size_t)N * 4, stream);
    hipMemsetAsync(cursor, 0, (size_t)N * 4, stream);
    hipMemsetAsync(cntg,   0, (size_t)G * 4, stream);
    hipMemsetAsync(S,      0, (size_t)5 * G * 64 * 4, stream);
    hipMemsetAsync(bnpart, 0, (size_t)5 * 32 * 128 * 4, stream);

    int nb_e = (E + 255) / 256;
    int nb_scan = (N + SCAN_ELEMS - 1) / SCAN_ELEMS;
    k_hist<<<nb_e, 256, 0, stream>>>(dstp, E, cntn, batch, N, cntg);
    k_scan1<<<nb_scan, 256, 0, stream>>>(cntn, N, rp, bsum);
    k_scan2<<<1, 128, 0, stream>>>(bsum, nb_scan, boffs);
    k_scan3<<<(N + 255) / 256, 256, 0, stream>>>(rp, N, boffs, E);
    k_fill<<<nb_e, 256, 0, stream>>>(srcp, dstp, E, rp, cursor, col);

    k_premm<<<512, 256, 0, stream>>>(x, W1a, B0, N);

    int nb_node = (N + 3) / 4;
    int nb_tile = (N + 63) / 64;

    // Layer 1 (W1a folded into k_premm): gather B0 -> B1, mlp B1 -> B0
    k_gather<true><<<nb_node, 256, 0, stream>>>(B0, B1, rp, col, nullptr, N);
    k_mlp<true><<<nb_tile, 256, 0, stream>>>(B1, B0, batch,
        nullptr, b1a, W1b, b1b, S, bnpart, N);
    k_bnstat<<<1, 64, 0, stream>>>(bnpart, gamma, beta, ab, ab + 64, N);

    for (int l = 0; l < 4; ++l) {
        k_gather<false><<<nb_node, 256, 0, stream>>>(B0, B1, rp, col,
            ab + l * 128, N);
        k_mlp<false><<<nb_tile, 256, 0, stream>>>(B1, B0, batch,
            Wa + l * 4096, ba + l * 64, Wb + l * 4096, bb + l * 64,
            S + (size_t)(l + 1) * G * 64,
            bnpart + (size_t)(l + 1) * 32 * 128, N);
        k_bnstat<<<1, 64, 0, stream>>>(
            bnpart + (size_t)(l + 1) * 32 * 128,
            gamma + (l + 1) * 64, beta + (l + 1) * 64,
            ab + (l + 1) * 128, ab + (l + 1) * 128 + 64, N);
    }

    k_final<<<(G + 3) / 4, 256, 0, stream>>>(S, ab, cntg, fc1W, fc1b, fc2W, fc2b,
                                             (float*)d_out, G);
}

// Round 6
// 831.932 us; speedup vs baseline: 1.8316x; 1.1717x over previous
//
#include <hip/hip_runtime.h>

// ---------------------------------------------------------------------------
// GIN (5 layers) + BN + graph pooling + MLP head, fp32.
// R6: (1) rank-trick CSR fill: the returning atomic moves to k_hist (rank[e]
//     stored coalesced); k_fill = coalesced reads + scattered store, no
//     atomic round-trip. (2) Layer-1 gather done in 11-dim space (x padded
//     to 16ch): 102 MB instead of 410 MB; k_mlp<FIRST> performs the 11x64
//     matvec from a transposed LDS tile (W1a via scalar pipe); k_premm and
//     the layer-1 64-dim gather are deleted. (3) single consolidated memset.
// ---------------------------------------------------------------------------

#define SCAN_ELEMS 1024

__global__ __launch_bounds__(256) void k_hist(const int* __restrict__ dst, int E,
        int* __restrict__ cnt_node, int* __restrict__ rank_,
        const int* __restrict__ batch, int N, int* __restrict__ cnt_graph,
        const float* __restrict__ x, float* __restrict__ x16) {
    int i = blockIdx.x * blockDim.x + threadIdx.x;
    if (i < E) rank_[i] = atomicAdd(&cnt_node[dst[i]], 1);
    if (i < N) {
        atomicAdd(&cnt_graph[batch[i]], 1);
#pragma unroll
        for (int k = 0; k < 11; ++k) x16[i * 16 + k] = x[i * 11 + k];
#pragma unroll
        for (int k = 11; k < 16; ++k) x16[i * 16 + k] = 0.f;
    }
}

__global__ __launch_bounds__(256) void k_scan1(const int* __restrict__ cnt, int n,
        int* __restrict__ rp, int* __restrict__ bsum) {
    __shared__ int sdata[256];
    int t = threadIdx.x;
    int base = blockIdx.x * SCAN_ELEMS + t * 4;
    int v0 = (base + 0 < n) ? cnt[base + 0] : 0;
    int v1 = (base + 1 < n) ? cnt[base + 1] : 0;
    int v2 = (base + 2 < n) ? cnt[base + 2] : 0;
    int v3 = (base + 3 < n) ? cnt[base + 3] : 0;
    int tsum = v0 + v1 + v2 + v3;
    sdata[t] = tsum;
    __syncthreads();
    for (int off = 1; off < 256; off <<= 1) {
        int val = (t >= off) ? sdata[t - off] : 0;
        __syncthreads();
        sdata[t] += val;
        __syncthreads();
    }
    int excl = sdata[t] - tsum;
    if (t == 255) bsum[blockIdx.x] = sdata[255];
    if (base + 0 < n) rp[base + 0] = excl;
    if (base + 1 < n) rp[base + 1] = excl + v0;
    if (base + 2 < n) rp[base + 2] = excl + v0 + v1;
    if (base + 3 < n) rp[base + 3] = excl + v0 + v1 + v2;
}

__global__ __launch_bounds__(128) void k_scan2(const int* __restrict__ bsum, int nb,
        int* __restrict__ boffs) {
    __shared__ int sd[128];
    int t = threadIdx.x;
    int v = (t < nb) ? bsum[t] : 0;
    sd[t] = v;
    __syncthreads();
    for (int off = 1; off < 128; off <<= 1) {
        int val = (t >= off) ? sd[t - off] : 0;
        __syncthreads();
        sd[t] += val;
        __syncthreads();
    }
    if (t < nb) boffs[t] = sd[t] - v;
}

__global__ __launch_bounds__(256) void k_scan3(int* __restrict__ rp, int n,
        const int* __restrict__ boffs, int E) {
    int i = blockIdx.x * blockDim.x + threadIdx.x;
    if (i < n) rp[i] += boffs[i / SCAN_ELEMS];
    if (i == 0) rp[n] = E;
}

__global__ __launch_bounds__(256) void k_fill(const int* __restrict__ src,
        const int* __restrict__ dst, const int* __restrict__ rank_, int E,
        const int* __restrict__ rp, int* __restrict__ col) {
    int e = blockIdx.x * blockDim.x + threadIdx.x;
    if (e < E) {
        col[rp[dst[e]] + rank_[e]] = src[e];
    }
}

// Layer-1 gather in padded 11->16 dim space: wave = 1 node, 4 edges per
// iteration (16 lanes per edge), unroll 2 -> 8 edges in flight.
__global__ __launch_bounds__(256, 8) void k_gather16(
        const float* __restrict__ x16, float* __restrict__ h16,
        const int* __restrict__ rp, const int* __restrict__ col, int N) {
    int lane = threadIdx.x & 63, wv = threadIdx.x >> 6;
    int n = blockIdx.x * 4 + wv;
    if (n >= N) return;
    int sub = lane >> 4, c = lane & 15;
    int start = rp[n], end = rp[n + 1];
    float s0 = 0.f, s1 = 0.f;
    int eb = start;
    for (; eb + 8 <= end; eb += 8) {
        int j0 = col[eb + sub];
        int j1 = col[eb + 4 + sub];
        s0 += x16[(size_t)j0 * 16 + c];
        s1 += x16[(size_t)j1 * 16 + c];
    }
    for (int e = eb + sub; e < end; e += 4) {
        s0 += x16[(size_t)col[e] * 16 + c];
    }
    float s = s0 + s1;
    s += __shfl_xor(s, 16);
    s += __shfl_xor(s, 32);
    if (lane < 16) {
        h16[(size_t)n * 16 + lane] = s + x16[(size_t)n * 16 + lane];
    }
}

// Gather (layers 2-5): one wave per node, lane = channel. s = v_n + sum_j v_j.
// Folds previous-layer BN affine: h2 = a*s + b*(1+deg). 8-deep load ILP.
__global__ __launch_bounds__(256, 8) void k_gather(
        const float* __restrict__ vin, float* __restrict__ agg,
        const int* __restrict__ rp, const int* __restrict__ col,
        const float* __restrict__ ab_prev, int N) {
    int lane = threadIdx.x & 63, wv = threadIdx.x >> 6;
    int n = blockIdx.x * 4 + wv;
    if (n >= N) return;
    float a = ab_prev[lane];
    float b = ab_prev[64 + lane];
    int start = rp[n], end = rp[n + 1];
    float s0 = vin[(size_t)n * 64 + lane];
    float s1 = 0.f, s2 = 0.f, s3 = 0.f, s4 = 0.f, s5 = 0.f, s6 = 0.f, s7 = 0.f;
    int e = start;
    for (; e + 8 <= end; e += 8) {
        int j0 = col[e + 0], j1 = col[e + 1], j2 = col[e + 2], j3 = col[e + 3];
        int j4 = col[e + 4], j5 = col[e + 5], j6 = col[e + 6], j7 = col[e + 7];
        s0 += vin[(size_t)j0 * 64 + lane];
        s1 += vin[(size_t)j1 * 64 + lane];
        s2 += vin[(size_t)j2 * 64 + lane];
        s3 += vin[(size_t)j3 * 64 + lane];
        s4 += vin[(size_t)j4 * 64 + lane];
        s5 += vin[(size_t)j5 * 64 + lane];
        s6 += vin[(size_t)j6 * 64 + lane];
        s7 += vin[(size_t)j7 * 64 + lane];
    }
    for (; e < end; ++e) s0 += vin[(size_t)col[e] * 64 + lane];
    float s = ((s0 + s1) + (s2 + s3)) + ((s4 + s5) + (s6 + s7));
    agg[(size_t)n * 64 + lane] = fmaf(a, s, b * (float)(1 + end - start));
}

// MLP: one block = one 64-node tile. k-chunked matvecs; weights via the
// scalar pipe (readfirstlane-uniform addresses -> s_load -> SGPR operands).
// FIRST: input is h16 (N x 16, 11 valid); matvec1 = 11xK from transposed
// LDS tile with W1a. Else: input is agg (N x 64); matvec1 = 64xK with Wa.
template <bool FIRST>
__global__ __launch_bounds__(256, 4) void k_mlp(
        const float* __restrict__ agg, float* __restrict__ vout,
        const int* __restrict__ batch,
        const float* __restrict__ Wa, const float* __restrict__ ba,
        const float* __restrict__ Wb, const float* __restrict__ bb,
        float* __restrict__ Sg, float* __restrict__ bnpart,
        int N) {
    __shared__ float hb[64 * 64];
    float4* hb4 = (float4*)hb;
    const int tid = threadIdx.x;
    const int lane = tid & 63;
    const int wv = tid >> 6;
    const int n0 = blockIdx.x * 64;
    const int l15 = lane & 15;
    // wave-uniform channel base, provably uniform -> weight reads use s_load
    const int c0 = __builtin_amdgcn_readfirstlane(wv) * 16;

    float acc[16];

    if (FIRST) {
        // ---- phase A': h16 tile -> transposed LDS hs[k][node] (aliases hb) --
        float* hs = hb;
        {
            int n = tid >> 2, kq = tid & 3;
            float4 v = make_float4(0.f, 0.f, 0.f, 0.f);
            if (n0 + n < N) v = ((const float4*)agg)[(size_t)n0 * 4 + tid];
            hs[(kq * 4 + 0) * 64 + n] = v.x;
            hs[(kq * 4 + 1) * 64 + n] = v.y;
            hs[(kq * 4 + 2) * 64 + n] = v.z;
            hs[(kq * 4 + 3) * 64 + n] = v.w;
        }
        __syncthreads();
        // ---- matvec1: t[c0+j] = relu(sum_{k<11} h[k]*W1a[k][c0+j] + ba) ----
#pragma unroll
        for (int j = 0; j < 16; ++j) acc[j] = ba[c0 + j];
#pragma unroll
        for (int k = 0; k < 11; ++k) {
            float hk = hs[k * 64 + lane];            // conflict-free
            const float* wr = Wa + k * 64 + c0;      // uniform -> s_load
#pragma unroll
            for (int j = 0; j < 16; ++j) acc[j] = fmaf(hk, wr[j], acc[j]);
        }
        __syncthreads();   // done reading hs; safe to overwrite hb
#pragma unroll
        for (int j4 = 0; j4 < 4; ++j4) {
            int q = wv * 4 + j4;
            hb4[lane * 16 + (q ^ l15)] = make_float4(
                fmaxf(acc[j4 * 4 + 0], 0.f), fmaxf(acc[j4 * 4 + 1], 0.f),
                fmaxf(acc[j4 * 4 + 2], 0.f), fmaxf(acc[j4 * 4 + 3], 0.f));
        }
        __syncthreads();
    } else {
        // ---- phase A: coalesced tile load -> LDS (swizzled) ----
        {
            const float4* a4 = (const float4*)(agg + (size_t)n0 * 64);
#pragma unroll
            for (int r = 0; r < 4; ++r) {
                int i = tid + r * 256;          // float4 index within tile
                int nt = i >> 4, q = i & 15;
                float4 v = make_float4(0.f, 0.f, 0.f, 0.f);
                if (n0 + nt < N) v = a4[i];
                hb4[nt * 16 + (q ^ (nt & 15))] = v;
            }
        }
        __syncthreads();
        // ---- matvec1: t[c0+j] = relu(sum_k h[k]*Wa[k][c0+j] + ba[c0+j]) ----
#pragma unroll
        for (int j = 0; j < 16; ++j) acc[j] = ba[c0 + j];
        for (int kc = 0; kc < 4; ++kc) {
            float hq[16];
#pragma unroll
            for (int q4 = 0; q4 < 4; ++q4) {
                float4 hv = hb4[lane * 16 + ((kc * 4 + q4) ^ l15)];
                hq[q4 * 4 + 0] = hv.x; hq[q4 * 4 + 1] = hv.y;
                hq[q4 * 4 + 2] = hv.z; hq[q4 * 4 + 3] = hv.w;
            }
            const float* wbase = Wa + (size_t)(kc * 16) * 64 + c0;   // uniform
#pragma unroll
            for (int kk = 0; kk < 16; ++kk) {
                float w[16];
#pragma unroll
                for (int j = 0; j < 16; ++j) w[j] = wbase[kk * 64 + j];  // s_load
                float hk = hq[kk];
#pragma unroll
                for (int j = 0; j < 16; ++j) acc[j] = fmaf(hk, w[j], acc[j]);
            }
        }
        __syncthreads();   // everyone done reading h from hb
#pragma unroll
        for (int j4 = 0; j4 < 4; ++j4) {
            int q = wv * 4 + j4;
            hb4[lane * 16 + (q ^ l15)] = make_float4(
                fmaxf(acc[j4 * 4 + 0], 0.f), fmaxf(acc[j4 * 4 + 1], 0.f),
                fmaxf(acc[j4 * 4 + 2], 0.f), fmaxf(acc[j4 * 4 + 3], 0.f));
        }
        __syncthreads();
    }

    // ---- matvec2: v[c0+j] = relu(sum_k t[k]*Wb[k][c0+j] + bb[c0+j]) ----
#pragma unroll
    for (int j = 0; j < 16; ++j) acc[j] = bb[c0 + j];
    for (int kc = 0; kc < 4; ++kc) {
        float hq[16];
#pragma unroll
        for (int q4 = 0; q4 < 4; ++q4) {
            float4 hv = hb4[lane * 16 + ((kc * 4 + q4) ^ l15)];
            hq[q4 * 4 + 0] = hv.x; hq[q4 * 4 + 1] = hv.y;
            hq[q4 * 4 + 2] = hv.z; hq[q4 * 4 + 3] = hv.w;
        }
        const float* wbase = Wb + (size_t)(kc * 16) * 64 + c0;       // uniform
#pragma unroll
        for (int kk = 0; kk < 16; ++kk) {
            float w[16];
#pragma unroll
            for (int j = 0; j < 16; ++j) w[j] = wbase[kk * 64 + j];  // s_load
            float hk = hq[kk];
#pragma unroll
            for (int j = 0; j < 16; ++j) acc[j] = fmaf(hk, w[j], acc[j]);
        }
    }
    __syncthreads();   // everyone done reading hb
    {
#pragma unroll
        for (int j4 = 0; j4 < 4; ++j4) {
            int q = wv * 4 + j4;
            hb4[lane * 16 + (q ^ l15)] = make_float4(
                fmaxf(acc[j4 * 4 + 0], 0.f), fmaxf(acc[j4 * 4 + 1], 0.f),
                fmaxf(acc[j4 * 4 + 2], 0.f), fmaxf(acc[j4 * 4 + 3], 0.f));
        }
    }
    __syncthreads();

    // ---- phase C: store + BN stats + graph pooling ----
    {
        int q = lane & 15;          // channel quad
        int ng = lane >> 4;         // node subgroup
        int base_nt = wv * 16;
        float4 bs = make_float4(0, 0, 0, 0), bq = make_float4(0, 0, 0, 0);

        bool full = (n0 + base_nt + 15) < N;            // wave-uniform
        int gf = 0, gl = -1;
        if (full) { gf = batch[n0 + base_nt]; gl = batch[n0 + base_nt + 15]; }

        if (full && gf == gl) {
            // fast path: whole 16-node group in one graph
            float4 pacc = make_float4(0, 0, 0, 0);
#pragma unroll
            for (int s2 = 0; s2 < 4; ++s2) {
                int nt = base_nt + s2 * 4 + ng;
                float4 v = hb4[nt * 16 + (q ^ (nt & 15))];
                *(float4*)(vout + (size_t)(n0 + nt) * 64 + q * 4) = v;
                bs.x += v.x; bs.y += v.y; bs.z += v.z; bs.w += v.w;
                bq.x += v.x * v.x; bq.y += v.y * v.y;
                bq.z += v.z * v.z; bq.w += v.w * v.w;
                pacc.x += v.x; pacc.y += v.y; pacc.z += v.z; pacc.w += v.w;
            }
#pragma unroll
            for (int off = 16; off < 64; off <<= 1) {
                pacc.x += __shfl_xor(pacc.x, off); pacc.y += __shfl_xor(pacc.y, off);
                pacc.z += __shfl_xor(pacc.z, off); pacc.w += __shfl_xor(pacc.w, off);
            }
            if (ng == 0) {
                atomicAdd(&Sg[gf * 64 + q * 4 + 0], pacc.x);
                atomicAdd(&Sg[gf * 64 + q * 4 + 1], pacc.y);
                atomicAdd(&Sg[gf * 64 + q * 4 + 2], pacc.z);
                atomicAdd(&Sg[gf * 64 + q * 4 + 3], pacc.w);
            }
        } else {
            // slow path: graph boundary inside the group (or tile tail)
            float4 pacc = make_float4(0, 0, 0, 0);
            int curg = -1;
#pragma unroll
            for (int s2 = 0; s2 < 4; ++s2) {
                int nt = base_nt + s2 * 4 + ng;
                int n = n0 + nt;
                if (n < N) {
                    float4 v = hb4[nt * 16 + (q ^ (nt & 15))];
                    *(float4*)(vout + (size_t)n * 64 + q * 4) = v;
                    bs.x += v.x; bs.y += v.y; bs.z += v.z; bs.w += v.w;
                    bq.x += v.x * v.x; bq.y += v.y * v.y;
                    bq.z += v.z * v.z; bq.w += v.w * v.w;
                    int g = batch[n];
                    if (g != curg) {
                        if (curg >= 0) {
                            atomicAdd(&Sg[curg * 64 + q * 4 + 0], pacc.x);
                            atomicAdd(&Sg[curg * 64 + q * 4 + 1], pacc.y);
                            atomicAdd(&Sg[curg * 64 + q * 4 + 2], pacc.z);
                            atomicAdd(&Sg[curg * 64 + q * 4 + 3], pacc.w);
                        }
                        curg = g;
                        pacc = make_float4(0, 0, 0, 0);
                    }
                    pacc.x += v.x; pacc.y += v.y; pacc.z += v.z; pacc.w += v.w;
                }
            }
            if (curg >= 0) {
                atomicAdd(&Sg[curg * 64 + q * 4 + 0], pacc.x);
                atomicAdd(&Sg[curg * 64 + q * 4 + 1], pacc.y);
                atomicAdd(&Sg[curg * 64 + q * 4 + 2], pacc.z);
                atomicAdd(&Sg[curg * 64 + q * 4 + 3], pacc.w);
            }
        }
#pragma unroll
        for (int off = 16; off < 64; off <<= 1) {
            bs.x += __shfl_xor(bs.x, off); bs.y += __shfl_xor(bs.y, off);
            bs.z += __shfl_xor(bs.z, off); bs.w += __shfl_xor(bs.w, off);
            bq.x += __shfl_xor(bq.x, off); bq.y += __shfl_xor(bq.y, off);
            bq.z += __shfl_xor(bq.z, off); bq.w += __shfl_xor(bq.w, off);
        }
        if (ng == 0) {
            float* bkt = bnpart + (blockIdx.x & 31) * 128;
            atomicAdd(&bkt[q * 4 + 0], bs.x);
            atomicAdd(&bkt[q * 4 + 1], bs.y);
            atomicAdd(&bkt[q * 4 + 2], bs.z);
            atomicAdd(&bkt[q * 4 + 3], bs.w);
            atomicAdd(&bkt[64 + q * 4 + 0], bq.x);
            atomicAdd(&bkt[64 + q * 4 + 1], bq.y);
            atomicAdd(&bkt[64 + q * 4 + 2], bq.z);
            atomicAdd(&bkt[64 + q * 4 + 3], bq.w);
        }
    }
}

__global__ void k_bnstat(const float* __restrict__ bnpart,
        const float* __restrict__ gamma, const float* __restrict__ beta,
        float* __restrict__ a, float* __restrict__ b, int N) {
    int c = threadIdx.x;  // 64 threads
    float s = 0.f, q = 0.f;
    for (int i = 0; i < 32; ++i) { s += bnpart[i * 128 + c]; q += bnpart[i * 128 + 64 + c]; }
    float invN = 1.0f / (float)N;
    float mu = s * invN;
    float var = q * invN - mu * mu;
    float ac = gamma[c] * rsqrtf(var + 1e-5f);
    a[c] = ac;
    b[c] = beta[c] - mu * ac;
}

// Head: z[g,320] = concat_l (a_l*S_l[g] + b_l*cnt[g]); out = relu(z@fc1+b)@fc2+b
__global__ __launch_bounds__(256) void k_final(
        const float* __restrict__ S, const float* __restrict__ ab,
        const int* __restrict__ cntg,
        const float* __restrict__ fc1W, const float* __restrict__ fc1b,
        const float* __restrict__ fc2W, const float* __restrict__ fc2b,
        float* __restrict__ out, int G) {
    __shared__ float zbuf[4][320];
    int tid = threadIdx.x;
    int lane = tid & 63, wv = tid >> 6;
    int g = blockIdx.x * 4 + wv;
    if (g >= G) return;
    float cf = (float)cntg[g];
#pragma unroll
    for (int l = 0; l < 5; ++l) {
        float a = ab[l * 128 + lane];
        float b = ab[l * 128 + 64 + lane];
        zbuf[wv][l * 64 + lane] = a * S[((size_t)l * G + g) * 64 + lane] + b * cf;
    }
    float acc = fc1b[lane];
    for (int k = 0; k < 320; ++k) acc += zbuf[wv][k] * fc1W[k * 64 + lane];
    float t = fmaxf(acc, 0.f);
    float r = t * fc2W[lane];
#pragma unroll
    for (int off = 32; off >= 1; off >>= 1) r += __shfl_xor(r, off);
    if (lane == 0) out[g] = r + fc2b[0];
}

extern "C" void kernel_launch(void* const* d_in, const int* in_sizes, int n_in,
                              void* d_out, int out_size, void* d_ws, size_t ws_size,
                              hipStream_t stream) {
    const float* x    = (const float*)d_in[0];
    const int*   ei   = (const int*)d_in[1];
    const int*   batch= (const int*)d_in[2];
    const float* W1a  = (const float*)d_in[3];
    const float* b1a  = (const float*)d_in[4];
    const float* W1b  = (const float*)d_in[5];
    const float* b1b  = (const float*)d_in[6];
    const float* Wa   = (const float*)d_in[7];
    const float* ba   = (const float*)d_in[8];
    const float* Wb   = (const float*)d_in[9];
    const float* bb   = (const float*)d_in[10];
    const float* gamma= (const float*)d_in[11];
    const float* beta = (const float*)d_in[12];
    const float* fc1W = (const float*)d_in[13];
    const float* fc1b = (const float*)d_in[14];
    const float* fc2W = (const float*)d_in[15];
    const float* fc2b = (const float*)d_in[16];

    const int N = in_sizes[2];
    const int E = in_sizes[1] / 2;
    const int G = out_size;
    const int* srcp = ei;
    const int* dstp = ei + E;

    char* p = (char*)d_ws;
    auto alloc = [&](size_t bytes) {
        char* r = p;
        p += (bytes + 255) & ~size_t(255);
        return r;
    };
    float* B0     = (float*)alloc((size_t)N * 64 * 4);
    float* B1     = (float*)alloc((size_t)N * 64 * 4);
    int*   col    = (int*)  alloc((size_t)E * 4);
    int*   rank_  = (int*)  alloc((size_t)E * 4);
    int*   rp     = (int*)  alloc((size_t)(N + 1) * 4);
    float* x16    = (float*)alloc((size_t)N * 16 * 4);
    float* h16    = (float*)alloc((size_t)N * 16 * 4);
    int*   bsum   = (int*)  alloc(512);
    int*   boffs  = (int*)  alloc(512);
    float* ab     = (float*)alloc(5 * 128 * 4);
    // ---- zeroed region (single memset) ----
    char*  z0     = p;
    int*   cntn   = (int*)  alloc((size_t)N * 4);
    int*   cntg   = (int*)  alloc((size_t)G * 4);
    float* S      = (float*)alloc((size_t)5 * G * 64 * 4);
    float* bnpart = (float*)alloc((size_t)5 * 32 * 128 * 4);
    size_t zbytes = (size_t)(p - z0);

    hipMemsetAsync(z0, 0, zbytes, stream);

    int nb_e = (E + 255) / 256;
    int nb_scan = (N + SCAN_ELEMS - 1) / SCAN_ELEMS;
    k_hist<<<nb_e, 256, 0, stream>>>(dstp, E, cntn, rank_, batch, N, cntg, x, x16);
    k_scan1<<<nb_scan, 256, 0, stream>>>(cntn, N, rp, bsum);
    k_scan2<<<1, 128, 0, stream>>>(bsum, nb_scan, boffs);
    k_scan3<<<(N + 255) / 256, 256, 0, stream>>>(rp, N, boffs, E);
    k_fill<<<nb_e, 256, 0, stream>>>(srcp, dstp, rank_, E, rp, col);

    int nb_node = (N + 3) / 4;
    int nb_tile = (N + 63) / 64;

    // Layer 1: 16-dim gather, then mlp<FIRST> does W1a from the 16-wide input
    k_gather16<<<nb_node, 256, 0, stream>>>(x16, h16, rp, col, N);
    k_mlp<true><<<nb_tile, 256, 0, stream>>>(h16, B0, batch,
        W1a, b1a, W1b, b1b, S, bnpart, N);
    k_bnstat<<<1, 64, 0, stream>>>(bnpart, gamma, beta, ab, ab + 64, N);

    for (int l = 0; l < 4; ++l) {
        k_gather<<<nb_node, 256, 0, stream>>>(B0, B1, rp, col,
            ab + l * 128, N);
        k_mlp<false><<<nb_tile, 256, 0, stream>>>(B1, B0, batch,
            Wa + l * 4096, ba + l * 64, Wb + l * 4096, bb + l * 64,
            S + (size_t)(l + 1) * G * 64,
            bnpart + (size_t)(l + 1) * 32 * 128, N);
        k_bnstat<<<1, 64, 0, stream>>>(
            bnpart + (size_t)(l + 1) * 32 * 128,
            gamma + (l + 1) * 64, beta + (l + 1) * 64,
            ab + (l + 1) * 128, ab + (l + 1) * 128 + 64, N);
    }

    k_final<<<(G + 3) / 4, 256, 0, stream>>>(S, ab, cntg, fc1W, fc1b, fc2W, fc2b,
                                             (float*)d_out, G);
}

// Round 8
// 817.967 us; speedup vs baseline: 1.8628x; 1.0171x over previous
//
#include <hip/hip_runtime.h>
#include <hip/hip_fp16.h>

// ---------------------------------------------------------------------------
// GIN (5 layers) + BN + graph pooling + MLP head.
// R8: R7's half-precision gather path, but FP16 (10-bit mantissa) instead of
//     bf16 (7-bit): same bandwidth (2B/elem), 8x lower quantization error.
//     R7 failed absmax 0.375 vs 0.37 -- bf16 error compounding over 5 layers;
//     fp16 brings it to ~0.05. Activations are post-BN/ReLU O(1..30), far
//     below fp16 range. All stats/matvecs stay fp32.
// ---------------------------------------------------------------------------

#define SCAN_ELEMS 1024

__device__ __forceinline__ unsigned short f2h(float f) {
    return __half_as_ushort(__float2half_rn(f));
}
__device__ __forceinline__ float h2f(unsigned short s) {
    return __half2float(__ushort_as_half(s));
}

__global__ __launch_bounds__(256) void k_prep(const float* __restrict__ x,
        unsigned short* __restrict__ x16h, const int* __restrict__ batch,
        int* __restrict__ cnt_graph, int N) {
    int i = blockIdx.x * blockDim.x + threadIdx.x;
    if (i < N) {
        atomicAdd(&cnt_graph[batch[i]], 1);
#pragma unroll
        for (int k = 0; k < 11; ++k) x16h[i * 16 + k] = f2h(x[i * 11 + k]);
#pragma unroll
        for (int k = 11; k < 16; ++k) x16h[i * 16 + k] = 0;
    }
}

__global__ __launch_bounds__(256) void k_hist(const int* __restrict__ dst, int E,
        int* __restrict__ cnt_node, int* __restrict__ rank_) {
    int i = blockIdx.x * blockDim.x + threadIdx.x;
    if (i < E) rank_[i] = atomicAdd(&cnt_node[dst[i]], 1);
}

__global__ __launch_bounds__(256) void k_scan1(const int* __restrict__ cnt, int n,
        int* __restrict__ rp, int* __restrict__ bsum) {
    __shared__ int sdata[256];
    int t = threadIdx.x;
    int base = blockIdx.x * SCAN_ELEMS + t * 4;
    int v0 = (base + 0 < n) ? cnt[base + 0] : 0;
    int v1 = (base + 1 < n) ? cnt[base + 1] : 0;
    int v2 = (base + 2 < n) ? cnt[base + 2] : 0;
    int v3 = (base + 3 < n) ? cnt[base + 3] : 0;
    int tsum = v0 + v1 + v2 + v3;
    sdata[t] = tsum;
    __syncthreads();
    for (int off = 1; off < 256; off <<= 1) {
        int val = (t >= off) ? sdata[t - off] : 0;
        __syncthreads();
        sdata[t] += val;
        __syncthreads();
    }
    int excl = sdata[t] - tsum;
    if (t == 255) bsum[blockIdx.x] = sdata[255];
    if (base + 0 < n) rp[base + 0] = excl;
    if (base + 1 < n) rp[base + 1] = excl + v0;
    if (base + 2 < n) rp[base + 2] = excl + v0 + v1;
    if (base + 3 < n) rp[base + 3] = excl + v0 + v1 + v2;
}

__global__ __launch_bounds__(128) void k_scan2(const int* __restrict__ bsum, int nb,
        int* __restrict__ boffs) {
    __shared__ int sd[128];
    int t = threadIdx.x;
    int v = (t < nb) ? bsum[t] : 0;
    sd[t] = v;
    __syncthreads();
    for (int off = 1; off < 128; off <<= 1) {
        int val = (t >= off) ? sd[t - off] : 0;
        __syncthreads();
        sd[t] += val;
        __syncthreads();
    }
    if (t < nb) boffs[t] = sd[t] - v;
}

__global__ __launch_bounds__(256) void k_scan3(int* __restrict__ rp, int n,
        const int* __restrict__ boffs, int E) {
    int i = blockIdx.x * blockDim.x + threadIdx.x;
    if (i < n) rp[i] += boffs[i / SCAN_ELEMS];
    if (i == 0) rp[n] = E;
}

__global__ __launch_bounds__(256) void k_fill(const int* __restrict__ src,
        const int* __restrict__ dst, const int* __restrict__ rank_, int E,
        const int* __restrict__ rp, int* __restrict__ col) {
    int e = blockIdx.x * blockDim.x + threadIdx.x;
    if (e < E) {
        __builtin_nontemporal_store(src[e], &col[rp[dst[e]] + rank_[e]]);
    }
}

// Layer-1 gather in padded 11->16 dim fp16 space: wave = 1 node, 4 edges per
// iteration (16 lanes per edge), unroll 2 -> 8 edges in flight. fp32 out.
__global__ __launch_bounds__(256, 8) void k_gather16(
        const unsigned short* __restrict__ x16h, float* __restrict__ h16,
        const int* __restrict__ rp, const int* __restrict__ col, int N) {
    int lane = threadIdx.x & 63, wv = threadIdx.x >> 6;
    int n = blockIdx.x * 4 + wv;
    if (n >= N) return;
    int sub = lane >> 4, c = lane & 15;
    int start = rp[n], end = rp[n + 1];
    float s0 = 0.f, s1 = 0.f;
    int eb = start;
    for (; eb + 8 <= end; eb += 8) {
        int j0 = col[eb + sub];
        int j1 = col[eb + 4 + sub];
        s0 += h2f(x16h[(size_t)j0 * 16 + c]);
        s1 += h2f(x16h[(size_t)j1 * 16 + c]);
    }
    for (int e = eb + sub; e < end; e += 4) {
        s0 += h2f(x16h[(size_t)col[e] * 16 + c]);
    }
    float s = s0 + s1;
    s += __shfl_xor(s, 16);
    s += __shfl_xor(s, 32);
    if (lane < 16) {
        h16[(size_t)n * 16 + lane] = s + h2f(x16h[(size_t)n * 16 + lane]);
    }
}

// Gather (layers 2-5): one wave per node, lane = channel, fp16 input.
// s = v_n + sum_j v_j; h2 = a*s + b*(1+deg) in fp32. 8-deep load ILP.
__global__ __launch_bounds__(256, 8) void k_gather(
        const unsigned short* __restrict__ vin, float* __restrict__ agg,
        const int* __restrict__ rp, const int* __restrict__ col,
        const float* __restrict__ ab_prev, int N) {
    int lane = threadIdx.x & 63, wv = threadIdx.x >> 6;
    int n = blockIdx.x * 4 + wv;
    if (n >= N) return;
    float a = ab_prev[lane];
    float b = ab_prev[64 + lane];
    int start = rp[n], end = rp[n + 1];
    float s0 = h2f(vin[(size_t)n * 64 + lane]);
    float s1 = 0.f, s2 = 0.f, s3 = 0.f, s4 = 0.f, s5 = 0.f, s6 = 0.f, s7 = 0.f;
    int e = start;
    for (; e + 8 <= end; e += 8) {
        int j0 = col[e + 0], j1 = col[e + 1], j2 = col[e + 2], j3 = col[e + 3];
        int j4 = col[e + 4], j5 = col[e + 5], j6 = col[e + 6], j7 = col[e + 7];
        s0 += h2f(vin[(size_t)j0 * 64 + lane]);
        s1 += h2f(vin[(size_t)j1 * 64 + lane]);
        s2 += h2f(vin[(size_t)j2 * 64 + lane]);
        s3 += h2f(vin[(size_t)j3 * 64 + lane]);
        s4 += h2f(vin[(size_t)j4 * 64 + lane]);
        s5 += h2f(vin[(size_t)j5 * 64 + lane]);
        s6 += h2f(vin[(size_t)j6 * 64 + lane]);
        s7 += h2f(vin[(size_t)j7 * 64 + lane]);
    }
    for (; e < end; ++e) s0 += h2f(vin[(size_t)col[e] * 64 + lane]);
    float s = ((s0 + s1) + (s2 + s3)) + ((s4 + s5) + (s6 + s7));
    agg[(size_t)n * 64 + lane] = fmaf(a, s, b * (float)(1 + end - start));
}

// MLP: one block = one 64-node tile. k-chunked matvecs; weights via the
// scalar pipe. Output stored as packed fp16 (stats/pooling use fp32 values).
template <bool FIRST>
__global__ __launch_bounds__(256, 4) void k_mlp(
        const float* __restrict__ agg, unsigned short* __restrict__ vout,
        const int* __restrict__ batch,
        const float* __restrict__ Wa, const float* __restrict__ ba,
        const float* __restrict__ Wb, const float* __restrict__ bb,
        float* __restrict__ Sg, float* __restrict__ bnpart,
        int N) {
    __shared__ float hb[64 * 64];
    float4* hb4 = (float4*)hb;
    const int tid = threadIdx.x;
    const int lane = tid & 63;
    const int wv = tid >> 6;
    const int n0 = blockIdx.x * 64;
    const int l15 = lane & 15;
    // wave-uniform channel base, provably uniform -> weight reads use s_load
    const int c0 = __builtin_amdgcn_readfirstlane(wv) * 16;

    float acc[16];

    if (FIRST) {
        // ---- phase A': h16 tile -> transposed LDS hs[k][node] (aliases hb) --
        float* hs = hb;
        {
            int n = tid >> 2, kq = tid & 3;
            float4 v = make_float4(0.f, 0.f, 0.f, 0.f);
            if (n0 + n < N) v = ((const float4*)agg)[(size_t)n0 * 4 + tid];
            hs[(kq * 4 + 0) * 64 + n] = v.x;
            hs[(kq * 4 + 1) * 64 + n] = v.y;
            hs[(kq * 4 + 2) * 64 + n] = v.z;
            hs[(kq * 4 + 3) * 64 + n] = v.w;
        }
        __syncthreads();
        // ---- matvec1: t[c0+j] = relu(sum_{k<11} h[k]*W1a[k][c0+j] + ba) ----
#pragma unroll
        for (int j = 0; j < 16; ++j) acc[j] = ba[c0 + j];
#pragma unroll
        for (int k = 0; k < 11; ++k) {
            float hk = hs[k * 64 + lane];            // conflict-free
            const float* wr = Wa + k * 64 + c0;      // uniform -> s_load
#pragma unroll
            for (int j = 0; j < 16; ++j) acc[j] = fmaf(hk, wr[j], acc[j]);
        }
        __syncthreads();   // done reading hs; safe to overwrite hb
#pragma unroll
        for (int j4 = 0; j4 < 4; ++j4) {
            int q = wv * 4 + j4;
            hb4[lane * 16 + (q ^ l15)] = make_float4(
                fmaxf(acc[j4 * 4 + 0], 0.f), fmaxf(acc[j4 * 4 + 1], 0.f),
                fmaxf(acc[j4 * 4 + 2], 0.f), fmaxf(acc[j4 * 4 + 3], 0.f));
        }
        __syncthreads();
    } else {
        // ---- phase A: coalesced tile load -> LDS (swizzled) ----
        {
            const float4* a4 = (const float4*)(agg + (size_t)n0 * 64);
#pragma unroll
            for (int r = 0; r < 4; ++r) {
                int i = tid + r * 256;          // float4 index within tile
                int nt = i >> 4, q = i & 15;
                float4 v = make_float4(0.f, 0.f, 0.f, 0.f);
                if (n0 + nt < N) v = a4[i];
                hb4[nt * 16 + (q ^ (nt & 15))] = v;
            }
        }
        __syncthreads();
        // ---- matvec1: t[c0+j] = relu(sum_k h[k]*Wa[k][c0+j] + ba[c0+j]) ----
#pragma unroll
        for (int j = 0; j < 16; ++j) acc[j] = ba[c0 + j];
        for (int kc = 0; kc < 4; ++kc) {
            float hq[16];
#pragma unroll
            for (int q4 = 0; q4 < 4; ++q4) {
                float4 hv = hb4[lane * 16 + ((kc * 4 + q4) ^ l15)];
                hq[q4 * 4 + 0] = hv.x; hq[q4 * 4 + 1] = hv.y;
                hq[q4 * 4 + 2] = hv.z; hq[q4 * 4 + 3] = hv.w;
            }
            const float* wbase = Wa + (size_t)(kc * 16) * 64 + c0;   // uniform
#pragma unroll
            for (int kk = 0; kk < 16; ++kk) {
                float w[16];
#pragma unroll
                for (int j = 0; j < 16; ++j) w[j] = wbase[kk * 64 + j];  // s_load
                float hk = hq[kk];
#pragma unroll
                for (int j = 0; j < 16; ++j) acc[j] = fmaf(hk, w[j], acc[j]);
            }
        }
        __syncthreads();   // everyone done reading h from hb
#pragma unroll
        for (int j4 = 0; j4 < 4; ++j4) {
            int q = wv * 4 + j4;
            hb4[lane * 16 + (q ^ l15)] = make_float4(
                fmaxf(acc[j4 * 4 + 0], 0.f), fmaxf(acc[j4 * 4 + 1], 0.f),
                fmaxf(acc[j4 * 4 + 2], 0.f), fmaxf(acc[j4 * 4 + 3], 0.f));
        }
        __syncthreads();
    }

    // ---- matvec2: v[c0+j] = relu(sum_k t[k]*Wb[k][c0+j] + bb[c0+j]) ----
#pragma unroll
    for (int j = 0; j < 16; ++j) acc[j] = bb[c0 + j];
    for (int kc = 0; kc < 4; ++kc) {
        float hq[16];
#pragma unroll
        for (int q4 = 0; q4 < 4; ++q4) {
            float4 hv = hb4[lane * 16 + ((kc * 4 + q4) ^ l15)];
            hq[q4 * 4 + 0] = hv.x; hq[q4 * 4 + 1] = hv.y;
            hq[q4 * 4 + 2] = hv.z; hq[q4 * 4 + 3] = hv.w;
        }
        const float* wbase = Wb + (size_t)(kc * 16) * 64 + c0;       // uniform
#pragma unroll
        for (int kk = 0; kk < 16; ++kk) {
            float w[16];
#pragma unroll
            for (int j = 0; j < 16; ++j) w[j] = wbase[kk * 64 + j];  // s_load
            float hk = hq[kk];
#pragma unroll
            for (int j = 0; j < 16; ++j) acc[j] = fmaf(hk, w[j], acc[j]);
        }
    }
    __syncthreads();   // everyone done reading hb
    {
#pragma unroll
        for (int j4 = 0; j4 < 4; ++j4) {
            int q = wv * 4 + j4;
            hb4[lane * 16 + (q ^ l15)] = make_float4(
                fmaxf(acc[j4 * 4 + 0], 0.f), fmaxf(acc[j4 * 4 + 1], 0.f),
                fmaxf(acc[j4 * 4 + 2], 0.f), fmaxf(acc[j4 * 4 + 3], 0.f));
        }
    }
    __syncthreads();

    // ---- phase C: fp16 store + BN stats + graph pooling (fp32) ----
    {
        int q = lane & 15;          // channel quad
        int ng = lane >> 4;         // node subgroup
        int base_nt = wv * 16;
        float4 bs = make_float4(0, 0, 0, 0), bq = make_float4(0, 0, 0, 0);

        bool full = (n0 + base_nt + 15) < N;            // wave-uniform
        int gf = 0, gl = -1;
        if (full) { gf = batch[n0 + base_nt]; gl = batch[n0 + base_nt + 15]; }

        if (full && gf == gl) {
            // fast path: whole 16-node group in one graph
            float4 pacc = make_float4(0, 0, 0, 0);
#pragma unroll
            for (int s2 = 0; s2 < 4; ++s2) {
                int nt = base_nt + s2 * 4 + ng;
                float4 v = hb4[nt * 16 + (q ^ (nt & 15))];
                ushort4 o;
                o.x = f2h(v.x); o.y = f2h(v.y); o.z = f2h(v.z); o.w = f2h(v.w);
                *(ushort4*)(vout + (size_t)(n0 + nt) * 64 + q * 4) = o;
                bs.x += v.x; bs.y += v.y; bs.z += v.z; bs.w += v.w;
                bq.x += v.x * v.x; bq.y += v.y * v.y;
                bq.z += v.z * v.z; bq.w += v.w * v.w;
                pacc.x += v.x; pacc.y += v.y; pacc.z += v.z; pacc.w += v.w;
            }
#pragma unroll
            for (int off = 16; off < 64; off <<= 1) {
                pacc.x += __shfl_xor(pacc.x, off); pacc.y += __shfl_xor(pacc.y, off);
                pacc.z += __shfl_xor(pacc.z, off); pacc.w += __shfl_xor(pacc.w, off);
            }
            if (ng == 0) {
                atomicAdd(&Sg[gf * 64 + q * 4 + 0], pacc.x);
                atomicAdd(&Sg[gf * 64 + q * 4 + 1], pacc.y);
                atomicAdd(&Sg[gf * 64 + q * 4 + 2], pacc.z);
                atomicAdd(&Sg[gf * 64 + q * 4 + 3], pacc.w);
            }
        } else {
            // slow path: graph boundary inside the group (or tile tail)
            float4 pacc = make_float4(0, 0, 0, 0);
            int curg = -1;
#pragma unroll
            for (int s2 = 0; s2 < 4; ++s2) {
                int nt = base_nt + s2 * 4 + ng;
                int n = n0 + nt;
                if (n < N) {
                    float4 v = hb4[nt * 16 + (q ^ (nt & 15))];
                    ushort4 o;
                    o.x = f2h(v.x); o.y = f2h(v.y); o.z = f2h(v.z); o.w = f2h(v.w);
                    *(ushort4*)(vout + (size_t)n * 64 + q * 4) = o;
                    bs.x += v.x; bs.y += v.y; bs.z += v.z; bs.w += v.w;
                    bq.x += v.x * v.x; bq.y += v.y * v.y;
                    bq.z += v.z * v.z; bq.w += v.w * v.w;
                    int g = batch[n];
                    if (g != curg) {
                        if (curg >= 0) {
                            atomicAdd(&Sg[curg * 64 + q * 4 + 0], pacc.x);
                            atomicAdd(&Sg[curg * 64 + q * 4 + 1], pacc.y);
                            atomicAdd(&Sg[curg * 64 + q * 4 + 2], pacc.z);
                            atomicAdd(&Sg[curg * 64 + q * 4 + 3], pacc.w);
                        }
                        curg = g;
                        pacc = make_float4(0, 0, 0, 0);
                    }
                    pacc.x += v.x; pacc.y += v.y; pacc.z += v.z; pacc.w += v.w;
                }
            }
            if (curg >= 0) {
                atomicAdd(&Sg[curg * 64 + q * 4 + 0], pacc.x);
                atomicAdd(&Sg[curg * 64 + q * 4 + 1], pacc.y);
                atomicAdd(&Sg[curg * 64 + q * 4 + 2], pacc.z);
                atomicAdd(&Sg[curg * 64 + q * 4 + 3], pacc.w);
            }
        }
#pragma unroll
        for (int off = 16; off < 64; off <<= 1) {
            bs.x += __shfl_xor(bs.x, off); bs.y += __shfl_xor(bs.y, off);
            bs.z += __shfl_xor(bs.z, off); bs.w += __shfl_xor(bs.w, off);
            bq.x += __shfl_xor(bq.x, off); bq.y += __shfl_xor(bq.y, off);
            bq.z += __shfl_xor(bq.z, off); bq.w += __shfl_xor(bq.w, off);
        }
        if (ng == 0) {
            float* bkt = bnpart + (blockIdx.x & 31) * 128;
            atomicAdd(&bkt[q * 4 + 0], bs.x);
            atomicAdd(&bkt[q * 4 + 1], bs.y);
            atomicAdd(&bkt[q * 4 + 2], bs.z);
            atomicAdd(&bkt[q * 4 + 3], bs.w);
            atomicAdd(&bkt[64 + q * 4 + 0], bq.x);
            atomicAdd(&bkt[64 + q * 4 + 1], bq.y);
            atomicAdd(&bkt[64 + q * 4 + 2], bq.z);
            atomicAdd(&bkt[64 + q * 4 + 3], bq.w);
        }
    }
}

__global__ void k_bnstat(const float* __restrict__ bnpart,
        const float* __restrict__ gamma, const float* __restrict__ beta,
        float* __restrict__ a, float* __restrict__ b, int N) {
    int c = threadIdx.x;  // 64 threads
    float s = 0.f, q = 0.f;
    for (int i = 0; i < 32; ++i) { s += bnpart[i * 128 + c]; q += bnpart[i * 128 + 64 + c]; }
    float invN = 1.0f / (float)N;
    float mu = s * invN;
    float var = q * invN - mu * mu;
    float ac = gamma[c] * rsqrtf(var + 1e-5f);
    a[c] = ac;
    b[c] = beta[c] - mu * ac;
}

// Head: z[g,320] = concat_l (a_l*S_l[g] + b_l*cnt[g]); out = relu(z@fc1+b)@fc2+b
__global__ __launch_bounds__(256) void k_final(
        const float* __restrict__ S, const float* __restrict__ ab,
        const int* __restrict__ cntg,
        const float* __restrict__ fc1W, const float* __restrict__ fc1b,
        const float* __restrict__ fc2W, const float* __restrict__ fc2b,
        float* __restrict__ out, int G) {
    __shared__ float zbuf[4][320];
    int tid = threadIdx.x;
    int lane = tid & 63, wv = tid >> 6;
    int g = blockIdx.x * 4 + wv;
    if (g >= G) return;
    float cf = (float)cntg[g];
#pragma unroll
    for (int l = 0; l < 5; ++l) {
        float a = ab[l * 128 + lane];
        float b = ab[l * 128 + 64 + lane];
        zbuf[wv][l * 64 + lane] = a * S[((size_t)l * G + g) * 64 + lane] + b * cf;
    }
    float acc = fc1b[lane];
    for (int k = 0; k < 320; ++k) acc += zbuf[wv][k] * fc1W[k * 64 + lane];
    float t = fmaxf(acc, 0.f);
    float r = t * fc2W[lane];
#pragma unroll
    for (int off = 32; off >= 1; off >>= 1) r += __shfl_xor(r, off);
    if (lane == 0) out[g] = r + fc2b[0];
}

extern "C" void kernel_launch(void* const* d_in, const int* in_sizes, int n_in,
                              void* d_out, int out_size, void* d_ws, size_t ws_size,
                              hipStream_t stream) {
    const float* x    = (const float*)d_in[0];
    const int*   ei   = (const int*)d_in[1];
    const int*   batch= (const int*)d_in[2];
    const float* W1a  = (const float*)d_in[3];
    const float* b1a  = (const float*)d_in[4];
    const float* W1b  = (const float*)d_in[5];
    const float* b1b  = (const float*)d_in[6];
    const float* Wa   = (const float*)d_in[7];
    const float* ba   = (const float*)d_in[8];
    const float* Wb   = (const float*)d_in[9];
    const float* bb   = (const float*)d_in[10];
    const float* gamma= (const float*)d_in[11];
    const float* beta = (const float*)d_in[12];
    const float* fc1W = (const float*)d_in[13];
    const float* fc1b = (const float*)d_in[14];
    const float* fc2W = (const float*)d_in[15];
    const float* fc2b = (const float*)d_in[16];

    const int N = in_sizes[2];
    const int E = in_sizes[1] / 2;
    const int G = out_size;
    const int* srcp = ei;
    const int* dstp = ei + E;

    char* p = (char*)d_ws;
    auto alloc = [&](size_t bytes) {
        char* r = p;
        p += (bytes + 255) & ~size_t(255);
        return r;
    };
    float*          agg  = (float*)alloc((size_t)N * 64 * 4);
    unsigned short* vb   = (unsigned short*)alloc((size_t)N * 64 * 2);
    int*   col    = (int*)  alloc((size_t)E * 4);
    int*   rank_  = (int*)  alloc((size_t)E * 4);
    int*   rp     = (int*)  alloc((size_t)(N + 1) * 4);
    unsigned short* x16h = (unsigned short*)alloc((size_t)N * 16 * 2);
    float* h16    = (float*)alloc((size_t)N * 16 * 4);
    int*   bsum   = (int*)  alloc(512);
    int*   boffs  = (int*)  alloc(512);
    float* ab     = (float*)alloc(5 * 128 * 4);
    // ---- zeroed region (single memset) ----
    char*  z0     = p;
    int*   cntn   = (int*)  alloc((size_t)N * 4);
    int*   cntg   = (int*)  alloc((size_t)G * 4);
    float* S      = (float*)alloc((size_t)5 * G * 64 * 4);
    float* bnpart = (float*)alloc((size_t)5 * 32 * 128 * 4);
    size_t zbytes = (size_t)(p - z0);

    hipMemsetAsync(z0, 0, zbytes, stream);

    int nb_e = (E + 255) / 256;
    int nb_n = (N + 255) / 256;
    int nb_scan = (N + SCAN_ELEMS - 1) / SCAN_ELEMS;
    k_prep<<<nb_n, 256, 0, stream>>>(x, x16h, batch, cntg, N);
    k_hist<<<nb_e, 256, 0, stream>>>(dstp, E, cntn, rank_);
    k_scan1<<<nb_scan, 256, 0, stream>>>(cntn, N, rp, bsum);
    k_scan2<<<1, 128, 0, stream>>>(bsum, nb_scan, boffs);
    k_scan3<<<(N + 255) / 256, 256, 0, stream>>>(rp, N, boffs, E);
    k_fill<<<nb_e, 256, 0, stream>>>(srcp, dstp, rank_, E, rp, col);

    int nb_node = (N + 3) / 4;
    int nb_tile = (N + 63) / 64;

    // Layer 1: 16-dim fp16 gather, then mlp<FIRST> does W1a from h16
    k_gather16<<<nb_node, 256, 0, stream>>>(x16h, h16, rp, col, N);
    k_mlp<true><<<nb_tile, 256, 0, stream>>>(h16, vb, batch,
        W1a, b1a, W1b, b1b, S, bnpart, N);
    k_bnstat<<<1, 64, 0, stream>>>(bnpart, gamma, beta, ab, ab + 64, N);

    for (int l = 0; l < 4; ++l) {
        k_gather<<<nb_node, 256, 0, stream>>>(vb, agg, rp, col,
            ab + l * 128, N);
        k_mlp<false><<<nb_tile, 256, 0, stream>>>(agg, vb, batch,
            Wa + l * 4096, ba + l * 64, Wb + l * 4096, bb + l * 64,
            S + (size_t)(l + 1) * G * 64,
            bnpart + (size_t)(l + 1) * 32 * 128, N);
        k_bnstat<<<1, 64, 0, stream>>>(
            bnpart + (size_t)(l + 1) * 32 * 128,
            gamma + (l + 1) * 64, beta + (l + 1) * 64,
            ab + (l + 1) * 128, ab + (l + 1) * 128 + 64, N);
    }

    k_final<<<(G + 3) / 4, 256, 0, stream>>>(S, ab, cntg, fc1W, fc1b, fc2W, fc2b,
                                             (float*)d_out, G);
}